// Round 13
// baseline (923.186 us; speedup 1.0000x reference)
//
#include <hip/hip_runtime.h>
#include <hip/hip_bf16.h>
#include <cstdint>

#define DEV __device__ __forceinline__

typedef __bf16 bf16x8 __attribute__((ext_vector_type(8)));
typedef float f32x4 __attribute__((ext_vector_type(4)));
typedef unsigned short ushort_t;
typedef ushort_t ushort8 __attribute__((ext_vector_type(8)));

DEV ushort_t f2bf(float f) {
  union { float f; uint32_t u; } x; x.f = f;
  uint32_t r = (x.u + 0x7fffu + ((x.u >> 16) & 1u)) >> 16;
  return (ushort_t)r;
}
DEV float bf2f(ushort_t b) {
  union { uint32_t u; float f; } x; x.u = ((uint32_t)b) << 16;
  return x.f;
}
DEV float gelu_exact(float v) {
  return 0.5f * v * (1.0f + erff(v * 0.70710678118654752f));
}
DEV void gload_lds16(const void* g, void* l) {
  __builtin_amdgcn_global_load_lds(
      (const __attribute__((address_space(1))) void*)g,
      (__attribute__((address_space(3))) void*)l, 16, 0, 0);
}

// ---------------- prep kernels ----------------

__global__ __launch_bounds__(64) void prep_scal(
    const float* __restrict__ conf, const float* __restrict__ age,
    const float* __restrict__ ev, float* __restrict__ base, float* __restrict__ cs) {
  int l = threadIdx.x;  // 64
  float e = ev[l];
  float m = e;
  #pragma unroll
  for (int d = 1; d < 64; d <<= 1) m = fmaxf(m, __shfl_xor(m, d));
  float freq = logf(e + 1.f) / (logf(m + 2.f) + 1e-8f);
  base[l] = 0.2f * expf(-age[l] * (1.f / 200.f)) + 0.15f * freq + 0.1f * conf[l] + 0.09f;
  cs[l] = 0.45f * conf[l];
}

__global__ __launch_bounds__(256) void prep_pnorm(
    const float* __restrict__ protos, const float* __restrict__ b_in,
    float* __restrict__ p_norm, float* __restrict__ dvec) {
  const int s = blockIdx.x, t = threadIdx.x;
  const float* p = protos + (size_t)s * 2048;
  float vals[8];
  float ss = 0.f, sb = 0.f;
  #pragma unroll
  for (int ii = 0; ii < 2; ++ii) {
    float4 v = *(const float4*)(p + t * 8 + ii * 4);
    float4 bi = *(const float4*)(b_in + t * 8 + ii * 4);
    vals[ii * 4 + 0] = v.x; vals[ii * 4 + 1] = v.y; vals[ii * 4 + 2] = v.z; vals[ii * 4 + 3] = v.w;
    ss += v.x * v.x + v.y * v.y + v.z * v.z + v.w * v.w;
    sb += v.x * bi.x + v.y * bi.y + v.z * bi.z + v.w * bi.w;
  }
  #pragma unroll
  for (int d = 1; d < 64; d <<= 1) { ss += __shfl_xor(ss, d); sb += __shfl_xor(sb, d); }
  __shared__ float red[8];
  if ((t & 63) == 0) { red[t >> 6] = ss; red[4 + (t >> 6)] = sb; }
  __syncthreads();
  ss = red[0] + red[1] + red[2] + red[3];
  sb = red[4] + red[5] + red[6] + red[7];
  float inv = 1.f / fmaxf(sqrtf(ss), 1e-12f);
  #pragma unroll
  for (int k = 0; k < 8; ++k) p_norm[(size_t)s * 2048 + t * 8 + k] = vals[k] * inv;
  if (t == 0) dvec[s] = sb * inv;
}

// ---------------- conversion kernels ----------------

__global__ __launch_bounds__(256) void conv_x(const float* __restrict__ x, ushort_t* __restrict__ xa) {
  size_t e = ((size_t)blockIdx.x * 256 + threadIdx.x) * 8;
  int row = (int)(e >> 11), col = (int)(e & 2047);
  float4 f0 = *(const float4*)(x + e);
  float4 f1 = *(const float4*)(x + e + 4);
  ushort8 o;
  o[0] = f2bf(f0.x); o[1] = f2bf(f0.y); o[2] = f2bf(f0.z); o[3] = f2bf(f0.w);
  o[4] = f2bf(f1.x); o[5] = f2bf(f1.y); o[6] = f2bf(f1.z); o[7] = f2bf(f1.w);
  *(ushort8*)(xa + (size_t)row * 2112 + col) = o;
}

__global__ __launch_bounds__(256) void conv_wbig(const float* __restrict__ W_in,
                                                 const float* __restrict__ Wr1,
                                                 ushort_t* __restrict__ wbig) {
  size_t e = ((size_t)blockIdx.x * 256 + threadIdx.x) * 8;
  int row = (int)(e >> 11), col = (int)(e & 2047);
  if (row >= 3072 && row < 3136) return;  // P2 region, filled by small_p2
  ushort8 o;
  if (row < 3072) {
    const float* src = (row < 2048) ? (W_in + (size_t)row * 2048 + col)
                                    : (Wr1 + (size_t)(row - 2048) * 2048 + col);
    float4 f0 = *(const float4*)(src);
    float4 f1 = *(const float4*)(src + 4);
    o[0] = f2bf(f0.x); o[1] = f2bf(f0.y); o[2] = f2bf(f0.z); o[3] = f2bf(f0.w);
    o[4] = f2bf(f1.x); o[5] = f2bf(f1.y); o[6] = f2bf(f1.z); o[7] = f2bf(f1.w);
  } else {
    o = ushort8{0, 0, 0, 0, 0, 0, 0, 0};
  }
  *(ushort8*)(wbig + (size_t)row * 2048 + col) = o;
}

__global__ __launch_bounds__(256) void conv_ww(const float* __restrict__ W_out,
                                               ushort_t* __restrict__ wwm) {
  size_t e = ((size_t)blockIdx.x * 256 + threadIdx.x) * 8;
  int n = (int)(e >> 11), c = (int)(e & 2047);
  float4 f0 = *(const float4*)(W_out + (size_t)n * 4096 + c);
  float4 f1 = *(const float4*)(W_out + (size_t)n * 4096 + c + 4);
  ushort8 o;
  o[0] = f2bf(f0.x); o[1] = f2bf(f0.y); o[2] = f2bf(f0.z); o[3] = f2bf(f0.w);
  o[4] = f2bf(f1.x); o[5] = f2bf(f1.y); o[6] = f2bf(f1.z); o[7] = f2bf(f1.w);
  *(ushort8*)(wwm + (size_t)n * 2112 + c) = o;
}

// P2[s][k] = sum_j p_norm[s][j] * W_in[j][k]  -> bf16 into wbig rows 3072+s
__global__ __launch_bounds__(256) void small_p2(const float* __restrict__ p_norm,
                                                const float* __restrict__ W_in,
                                                ushort_t* __restrict__ wbig) {
  __shared__ float pn[8][128];
  const int t = threadIdx.x;
  const int k = blockIdx.x * 128 + (t & 127);
  const int sh = t >> 7;  // 0/1
  const int s0 = blockIdx.y * 8;
  float acc[4] = {0.f, 0.f, 0.f, 0.f};
  for (int j0 = 0; j0 < 2048; j0 += 128) {
    __syncthreads();
    {
      int sl = t >> 5;           // 0..7
      int j4 = (t & 31) * 4;     // 0..124
      *(float4*)&pn[sl][j4] = *(const float4*)&p_norm[(size_t)(s0 + sl) * 2048 + j0 + j4];
    }
    __syncthreads();
    #pragma unroll 8
    for (int jj = 0; jj < 128; ++jj) {
      float wv = W_in[(size_t)(j0 + jj) * 2048 + k];
      #pragma unroll
      for (int i = 0; i < 4; ++i) acc[i] += pn[sh * 4 + i][jj] * wv;
    }
  }
  #pragma unroll
  for (int i = 0; i < 4; ++i)
    wbig[(size_t)(3072 + s0 + sh * 4 + i) * 2048 + k] = f2bf(acc[i]);
}

// Rt[n][s] = sum_k protos[s][k] * W_out[n][2048+k] -> bf16 into wwm cols 2048+s
__global__ __launch_bounds__(256) void small_R(const float* __restrict__ protos,
                                               const float* __restrict__ W_out,
                                               ushort_t* __restrict__ wwm) {
  __shared__ float pch[64][68];
  __shared__ float wch[16][68];
  const int t = threadIdx.x;
  const int n_loc = t >> 4;  // 0..15
  const int sb = t & 15;
  const int n0 = blockIdx.x * 16;
  float acc[4] = {0.f, 0.f, 0.f, 0.f};
  for (int k0 = 0; k0 < 2048; k0 += 64) {
    __syncthreads();
    #pragma unroll
    for (int ii = 0; ii < 4; ++ii) {
      int lin4 = t * 4 + ii;      // 0..1023
      int s = lin4 >> 4;          // 0..63
      int k4 = (lin4 & 15) * 4;
      *(float4*)&pch[s][k4] = *(const float4*)&protos[(size_t)s * 2048 + k0 + k4];
    }
    {
      int n_l = t >> 4;
      int k4 = (t & 15) * 4;
      *(float4*)&wch[n_l][k4] = *(const float4*)&W_out[(size_t)(n0 + n_l) * 4096 + 2048 + k0 + k4];
    }
    __syncthreads();
    #pragma unroll 8
    for (int kk = 0; kk < 64; ++kk) {
      float wv = wch[n_loc][kk];
      #pragma unroll
      for (int i = 0; i < 4; ++i) acc[i] += pch[sb + 16 * i][kk] * wv;
    }
  }
  #pragma unroll
  for (int i = 0; i < 4; ++i)
    wwm[(size_t)(n0 + n_loc) * 2112 + 2048 + sb + 16 * i] = f2bf(acc[i]);
}

// ---------------- HEAD GEMM (bf16, m97 tile, DOUBLE-BUFFERED LDS, 1 barrier/K-step) ------
// T3 minimum-2-phase: stage next K-tile into the other static buffer BEFORE computing the
// current one, one __syncthreads per K-step (compiler inserts the vmcnt drain there, after
// MFMAs are issued -> load latency hides under compute). Four distinct __shared__ arrays
// keep buffer selection compile-time. Epilogue identical to R12 (race-free rn2 partials).
__global__ __launch_bounds__(256) void gemm_head(
    const ushort_t* __restrict__ A, const ushort_t* __restrict__ Bw,
    const float* __restrict__ bias0, const float* __restrict__ bias1,
    float* __restrict__ rn2part, ushort_t* __restrict__ out1, float* __restrict__ out2) {
  __shared__ ushort_t As0[128 * 32], As1[128 * 32];
  __shared__ ushort_t Bs0[128 * 32], Bs1[128 * 32];
  const int tid = threadIdx.x;
  const int w = tid >> 6, l = tid & 63;
  const int bm = blockIdx.x * 128;
  const int bn = blockIdx.y * 128;
  const int srow = tid >> 2;
  const int scol = (tid & 3) * 8;
  const int wm = (w >> 1) * 64, wn = (w & 1) * 64;
  const int lr = l & 15, lk = (l >> 4) * 8;

  f32x4 acc[4][4];
  #pragma unroll
  for (int i = 0; i < 4; ++i)
    #pragma unroll
    for (int j = 0; j < 4; ++j) acc[i][j] = f32x4{0.f, 0.f, 0.f, 0.f};

  auto stage = [&](ushort_t* Ad, ushort_t* Bd, int k0) {
    #pragma unroll
    for (int r = 0; r < 2; ++r) {
      int row = srow + r * 64;
      gload_lds16(A + (size_t)(bm + row) * 2112 + k0 + scol,
                  (char*)Ad + (size_t)(r * 256 + tid) * 16);
      gload_lds16(Bw + (size_t)(bn + row) * 2048 + k0 + scol,
                  (char*)Bd + (size_t)(r * 256 + tid) * 16);
    }
  };
  auto compute = [&](const ushort_t* Asrc, const ushort_t* Bsrc) {
    bf16x8 af[4], bf_[4];
    #pragma unroll
    for (int i = 0; i < 4; ++i) af[i] = *(const bf16x8*)&Asrc[(wm + i * 16 + lr) * 32 + lk];
    #pragma unroll
    for (int j = 0; j < 4; ++j) bf_[j] = *(const bf16x8*)&Bsrc[(wn + j * 16 + lr) * 32 + lk];
    #pragma unroll
    for (int i = 0; i < 4; ++i)
      #pragma unroll
      for (int j = 0; j < 4; ++j)
        acc[i][j] = __builtin_amdgcn_mfma_f32_16x16x32_bf16(af[i], bf_[j], acc[i][j], 0, 0, 0);
  };

  stage(As0, Bs0, 0);
  __syncthreads();
  for (int k0 = 0; k0 < 2048; k0 += 64) {
    if (k0 + 32 < 2048) stage(As1, Bs1, k0 + 32);
    compute(As0, Bs0);
    __syncthreads();
    if (k0 + 64 < 2048) stage(As0, Bs0, k0 + 64);
    compute(As1, Bs1);
    __syncthreads();
  }

  const int lg = l >> 4;
  #pragma unroll
  for (int i = 0; i < 4; ++i) {
    #pragma unroll
    for (int q = 0; q < 4; ++q) {
      const int grow = bm + wm + i * 16 + lg * 4 + q;
      float ss = 0.f;
      #pragma unroll
      for (int j = 0; j < 4; ++j) {
        const int gcol = bn + wn + j * 16 + lr;
        float v = acc[i][j][q];
        if (gcol < 2048) {
          v += bias0[gcol];
          ss += v * v;
        } else if (gcol < 3072) {
          v += bias1[gcol - 2048];
          out1[(size_t)grow * 1024 + (gcol - 2048)] = f2bf(gelu_exact(v));
        } else if (gcol < 3136) {
          out2[(size_t)grow * 64 + (gcol - 3072)] = v;
        }
      }
      if (bn < 2048) {
        ss += __shfl_xor(ss, 1);
        ss += __shfl_xor(ss, 2);
        ss += __shfl_xor(ss, 4);
        ss += __shfl_xor(ss, 8);
        if (lr == 0) rn2part[(size_t)grow * 16 + blockIdx.y] = ss;
      }
    }
  }
}

// ---------------- OUT GEMM (bf16, DOUBLE-BUFFERED, residual from bf16 xa) ----------------
__global__ __launch_bounds__(256) void gemm_out(
    const ushort_t* __restrict__ A, const ushort_t* __restrict__ Bw,
    const float* __restrict__ bias0, float* __restrict__ out0) {
  __shared__ ushort_t As0[128 * 32], As1[128 * 32];
  __shared__ ushort_t Bs0[128 * 32], Bs1[128 * 32];
  const int tid = threadIdx.x;
  const int w = tid >> 6, l = tid & 63;
  const int bm = blockIdx.x * 128;
  const int bn = blockIdx.y * 128;
  const int srow = tid >> 2;
  const int scol = (tid & 3) * 8;
  const int wm = (w >> 1) * 64, wn = (w & 1) * 64;
  const int lr = l & 15, lk = (l >> 4) * 8;

  f32x4 acc[4][4];
  #pragma unroll
  for (int i = 0; i < 4; ++i)
    #pragma unroll
    for (int j = 0; j < 4; ++j) acc[i][j] = f32x4{0.f, 0.f, 0.f, 0.f};

  auto stage = [&](ushort_t* Ad, ushort_t* Bd, int k0) {
    #pragma unroll
    for (int r = 0; r < 2; ++r) {
      int row = srow + r * 64;
      gload_lds16(A + (size_t)(bm + row) * 2112 + k0 + scol,
                  (char*)Ad + (size_t)(r * 256 + tid) * 16);
      gload_lds16(Bw + (size_t)(bn + row) * 2112 + k0 + scol,
                  (char*)Bd + (size_t)(r * 256 + tid) * 16);
    }
  };
  auto compute = [&](const ushort_t* Asrc, const ushort_t* Bsrc) {
    bf16x8 af[4], bf_[4];
    #pragma unroll
    for (int i = 0; i < 4; ++i) af[i] = *(const bf16x8*)&Asrc[(wm + i * 16 + lr) * 32 + lk];
    #pragma unroll
    for (int j = 0; j < 4; ++j) bf_[j] = *(const bf16x8*)&Bsrc[(wn + j * 16 + lr) * 32 + lk];
    #pragma unroll
    for (int i = 0; i < 4; ++i)
      #pragma unroll
      for (int j = 0; j < 4; ++j)
        acc[i][j] = __builtin_amdgcn_mfma_f32_16x16x32_bf16(af[i], bf_[j], acc[i][j], 0, 0, 0);
  };

  stage(As0, Bs0, 0);
  __syncthreads();
  for (int k0 = 0; k0 < 2112; k0 += 64) {
    if (k0 + 32 < 2112) stage(As1, Bs1, k0 + 32);
    compute(As0, Bs0);
    __syncthreads();
    if (k0 + 64 < 2112) stage(As0, Bs0, k0 + 64);
    compute(As1, Bs1);
    __syncthreads();
  }

  const int lg = l >> 4;
  #pragma unroll
  for (int i = 0; i < 4; ++i)
    #pragma unroll
    for (int j = 0; j < 4; ++j)
      #pragma unroll
      for (int q = 0; q < 4; ++q) {
        const int grow = bm + wm + i * 16 + lg * 4 + q;
        const int gcol = bn + wn + j * 16 + lr;
        float v = acc[i][j][q] + bias0[gcol];
        float g = gelu_exact(v);
        out0[(size_t)grow * 2048 + gcol] = g + bf2f(A[(size_t)grow * 2112 + gcol]);
      }
}

// ---------------- attention / salience kernel (1 wave per row) ----------------
__global__ __launch_bounds__(256) void attn_k(
    const ushort_t* __restrict__ r_bf, const float* __restrict__ Wr2,
    const float* __restrict__ br2, const float* __restrict__ rn2p,
    const float* __restrict__ rproj, const float* __restrict__ dvec,
    const float* __restrict__ base, const float* __restrict__ cs,
    ushort_t* __restrict__ xa) {
  const int b = blockIdx.x * 4 + (threadIdx.x >> 6);
  const int l = threadIdx.x & 63;
  const ushort_t* rrow = r_bf + (size_t)b * 1024;
  float t0 = 0.f, t1 = 0.f, t2 = 0.f, t3 = 0.f;
  #pragma unroll
  for (int m = 0; m < 16; ++m) {
    int k = l + m * 64;
    float rv = bf2f(rrow[k]);
    t0 += rv * Wr2[k];
    t1 += rv * Wr2[1024 + k];
    t2 += rv * Wr2[2048 + k];
    t3 += rv * Wr2[3072 + k];
  }
  #pragma unroll
  for (int d = 1; d < 64; d <<= 1) {
    t0 += __shfl_xor(t0, d); t1 += __shfl_xor(t1, d);
    t2 += __shfl_xor(t2, d); t3 += __shfl_xor(t3, d);
  }
  t0 += br2[0]; t1 += br2[1]; t2 += br2[2]; t3 += br2[3];
  float mx = fmaxf(fmaxf(t0, t1), fmaxf(t2, t3));
  float e0 = expf(t0 - mx), e1 = expf(t1 - mx), e2 = expf(t2 - mx), e3 = expf(t3 - mx);
  float sinv = 1.f / (e0 + e1 + e2 + e3);
  float tw0 = e0 * sinv, tw1 = e1 * sinv, tw2 = e2 * sinv, tw3 = e3 * sinv;
  const int ty = l >> 4;
  float twv = (ty == 0) ? tw0 : ((ty == 1) ? tw1 : ((ty == 2) ? tw2 : tw3));

  float rsum = 0.f;
  #pragma unroll
  for (int t = 0; t < 16; ++t) rsum += rn2p[(size_t)b * 16 + t];
  float inv = 1.f / fmaxf(sqrtf(rsum), 1e-12f);
  float rp = rproj[(size_t)b * 64 + l] + dvec[l];
  float sal = cs[l] * twv * (rp * inv) + base[l];
  sal = fminf(fmaxf(sal, 0.f), 1.f);
  float logit = sal * (1.f / 0.07f);
  float lm = logit;
  #pragma unroll
  for (int d = 1; d < 64; d <<= 1) lm = fmaxf(lm, __shfl_xor(lm, d));
  float ex = expf(logit - lm);
  float es = ex;
  #pragma unroll
  for (int d = 1; d < 64; d <<= 1) es += __shfl_xor(es, d);
  float attn = ex / es;
  xa[(size_t)b * 2112 + 2048 + l] = f2bf(attn);
}

// ---------------- LayerNorm (in-place on d_out) ----------------
__global__ __launch_bounds__(256) void ln_k(float* __restrict__ y,
                                            const float* __restrict__ lw,
                                            const float* __restrict__ lb) {
  const int b = blockIdx.x, t = threadIdx.x;
  float* row = y + (size_t)b * 2048;
  float4 v0 = *(const float4*)(row + t * 8);
  float4 v1 = *(const float4*)(row + t * 8 + 4);
  float s = v0.x + v0.y + v0.z + v0.w + v1.x + v1.y + v1.z + v1.w;
  float s2 = v0.x * v0.x + v0.y * v0.y + v0.z * v0.z + v0.w * v0.w +
             v1.x * v1.x + v1.y * v1.y + v1.z * v1.z + v1.w * v1.w;
  #pragma unroll
  for (int d = 1; d < 64; d <<= 1) { s += __shfl_xor(s, d); s2 += __shfl_xor(s2, d); }
  __shared__ float red[8];
  if ((t & 63) == 0) { red[t >> 6] = s; red[4 + (t >> 6)] = s2; }
  __syncthreads();
  float ts = red[0] + red[1] + red[2] + red[3];
  float ts2 = red[4] + red[5] + red[6] + red[7];
  const float mu = ts * (1.f / 2048.f);
  const float inv = 1.f / sqrtf(ts2 * (1.f / 2048.f) - mu * mu + 1e-5f);
  float4 w0 = *(const float4*)(lw + t * 8), w1 = *(const float4*)(lw + t * 8 + 4);
  float4 b0 = *(const float4*)(lb + t * 8), b1 = *(const float4*)(lb + t * 8 + 4);
  float4 o0, o1;
  o0.x = (v0.x - mu) * inv * w0.x + b0.x;
  o0.y = (v0.y - mu) * inv * w0.y + b0.y;
  o0.z = (v0.z - mu) * inv * w0.z + b0.z;
  o0.w = (v0.w - mu) * inv * w0.w + b0.w;
  o1.x = (v1.x - mu) * inv * w1.x + b1.x;
  o1.y = (v1.y - mu) * inv * w1.y + b1.y;
  o1.z = (v1.z - mu) * inv * w1.z + b1.z;
  o1.w = (v1.w - mu) * inv * w1.w + b1.w;
  *(float4*)(row + t * 8) = o0;
  *(float4*)(row + t * 8 + 4) = o1;
}

// ---------------- launch ----------------
extern "C" void kernel_launch(void* const* d_in, const int* in_sizes, int n_in,
                              void* d_out, int out_size, void* d_ws, size_t ws_size,
                              hipStream_t stream) {
  const float* x      = (const float*)d_in[0];
  const float* protos = (const float*)d_in[1];
  const float* conf   = (const float*)d_in[2];
  const float* age    = (const float*)d_in[3];
  const float* ev     = (const float*)d_in[4];
  const float* W_in   = (const float*)d_in[5];
  const float* b_in   = (const float*)d_in[6];
  const float* Wr1    = (const float*)d_in[7];
  const float* br1    = (const float*)d_in[8];
  const float* Wr2    = (const float*)d_in[9];
  const float* br2    = (const float*)d_in[10];
  const float* W_out  = (const float*)d_in[11];
  const float* b_out  = (const float*)d_in[12];
  const float* ln_w   = (const float*)d_in[13];
  const float* ln_b   = (const float*)d_in[14];
  float* out = (float*)d_out;

  char* ws = (char*)d_ws;
  size_t off = 0;
  auto take = [&](size_t bytes) {
    char* p = ws + off;
    off = (off + bytes + 255) & ~(size_t)255;
    return p;
  };
  ushort_t* xa     = (ushort_t*)take((size_t)16384 * 2112 * 2);
  ushort_t* wbig   = (ushort_t*)take((size_t)3200 * 2048 * 2);
  ushort_t* wwm    = (ushort_t*)take((size_t)2048 * 2112 * 2);
  ushort_t* rbf    = (ushort_t*)take((size_t)16384 * 1024 * 2);
  float*    rproj  = (float*)take((size_t)16384 * 64 * 4);
  float*    rn2p   = (float*)take((size_t)16384 * 16 * 4);
  float*    pnorm  = (float*)take((size_t)64 * 2048 * 4);
  float*    base   = (float*)take(256);
  float*    cs     = (float*)take(256);
  float*    dvec   = (float*)take(256);
  (void)in_sizes; (void)n_in; (void)out_size; (void)ws_size;

  prep_scal<<<1, 64, 0, stream>>>(conf, age, ev, base, cs);
  prep_pnorm<<<64, 256, 0, stream>>>(protos, b_in, pnorm, dvec);
  conv_x<<<16384, 256, 0, stream>>>(x, xa);
  conv_wbig<<<3200, 256, 0, stream>>>(W_in, Wr1, wbig);
  conv_ww<<<2048, 256, 0, stream>>>(W_out, wwm);
  small_p2<<<dim3(16, 8), 256, 0, stream>>>(pnorm, W_in, wbig);
  small_R<<<128, 256, 0, stream>>>(protos, W_out, wwm);
  // HEAD GEMM: M=16384, N=3200 (rows 3136-3199 zero), K=2048
  gemm_head<<<dim3(128, 25), 256, 0, stream>>>(xa, wbig, b_in, br1, rn2p, rbf, rproj);
  attn_k<<<4096, 256, 0, stream>>>(rbf, Wr2, br2, rn2p, rproj, dvec, base, cs, xa);
  // OUT GEMM: M=16384, N=2048, K=2112
  gemm_out<<<dim3(128, 16), 256, 0, stream>>>(xa, wwm, b_out, out);
  ln_k<<<16384, 256, 0, stream>>>(out, ln_w, ln_b);
}

// Round 14
// 829.353 us; speedup vs baseline: 1.1131x; 1.1131x over previous
//
#include <hip/hip_runtime.h>
#include <hip/hip_bf16.h>
#include <cstdint>

#define DEV __device__ __forceinline__

typedef __bf16 bf16x8 __attribute__((ext_vector_type(8)));
typedef float f32x4 __attribute__((ext_vector_type(4)));
typedef unsigned short ushort_t;
typedef ushort_t ushort8 __attribute__((ext_vector_type(8)));

DEV ushort_t f2bf(float f) {
  union { float f; uint32_t u; } x; x.f = f;
  uint32_t r = (x.u + 0x7fffu + ((x.u >> 16) & 1u)) >> 16;
  return (ushort_t)r;
}
DEV float bf2f(ushort_t b) {
  union { uint32_t u; float f; } x; x.u = ((uint32_t)b) << 16;
  return x.f;
}
DEV float gelu_exact(float v) {
  return 0.5f * v * (1.0f + erff(v * 0.70710678118654752f));
}
DEV void gload_lds16(const void* g, void* l) {
  __builtin_amdgcn_global_load_lds(
      (const __attribute__((address_space(1))) void*)g,
      (__attribute__((address_space(3))) void*)l, 16, 0, 0);
}

// ---------------- prep kernels ----------------

__global__ __launch_bounds__(64) void prep_scal(
    const float* __restrict__ conf, const float* __restrict__ age,
    const float* __restrict__ ev, float* __restrict__ base, float* __restrict__ cs) {
  int l = threadIdx.x;  // 64
  float e = ev[l];
  float m = e;
  #pragma unroll
  for (int d = 1; d < 64; d <<= 1) m = fmaxf(m, __shfl_xor(m, d));
  float freq = logf(e + 1.f) / (logf(m + 2.f) + 1e-8f);
  base[l] = 0.2f * expf(-age[l] * (1.f / 200.f)) + 0.15f * freq + 0.1f * conf[l] + 0.09f;
  cs[l] = 0.45f * conf[l];
}

__global__ __launch_bounds__(256) void prep_pnorm(
    const float* __restrict__ protos, const float* __restrict__ b_in,
    float* __restrict__ p_norm, float* __restrict__ dvec) {
  const int s = blockIdx.x, t = threadIdx.x;
  const float* p = protos + (size_t)s * 2048;
  float vals[8];
  float ss = 0.f, sb = 0.f;
  #pragma unroll
  for (int ii = 0; ii < 2; ++ii) {
    float4 v = *(const float4*)(p + t * 8 + ii * 4);
    float4 bi = *(const float4*)(b_in + t * 8 + ii * 4);
    vals[ii * 4 + 0] = v.x; vals[ii * 4 + 1] = v.y; vals[ii * 4 + 2] = v.z; vals[ii * 4 + 3] = v.w;
    ss += v.x * v.x + v.y * v.y + v.z * v.z + v.w * v.w;
    sb += v.x * bi.x + v.y * bi.y + v.z * bi.z + v.w * bi.w;
  }
  #pragma unroll
  for (int d = 1; d < 64; d <<= 1) { ss += __shfl_xor(ss, d); sb += __shfl_xor(sb, d); }
  __shared__ float red[8];
  if ((t & 63) == 0) { red[t >> 6] = ss; red[4 + (t >> 6)] = sb; }
  __syncthreads();
  ss = red[0] + red[1] + red[2] + red[3];
  sb = red[4] + red[5] + red[6] + red[7];
  float inv = 1.f / fmaxf(sqrtf(ss), 1e-12f);
  #pragma unroll
  for (int k = 0; k < 8; ++k) p_norm[(size_t)s * 2048 + t * 8 + k] = vals[k] * inv;
  if (t == 0) dvec[s] = sb * inv;
}

// ---------------- conversion kernels ----------------

__global__ __launch_bounds__(256) void conv_x(const float* __restrict__ x, ushort_t* __restrict__ xa) {
  size_t e = ((size_t)blockIdx.x * 256 + threadIdx.x) * 8;
  int row = (int)(e >> 11), col = (int)(e & 2047);
  float4 f0 = *(const float4*)(x + e);
  float4 f1 = *(const float4*)(x + e + 4);
  ushort8 o;
  o[0] = f2bf(f0.x); o[1] = f2bf(f0.y); o[2] = f2bf(f0.z); o[3] = f2bf(f0.w);
  o[4] = f2bf(f1.x); o[5] = f2bf(f1.y); o[6] = f2bf(f1.z); o[7] = f2bf(f1.w);
  *(ushort8*)(xa + (size_t)row * 2112 + col) = o;
}

__global__ __launch_bounds__(256) void conv_wbig(const float* __restrict__ W_in,
                                                 const float* __restrict__ Wr1,
                                                 ushort_t* __restrict__ wbig) {
  size_t e = ((size_t)blockIdx.x * 256 + threadIdx.x) * 8;
  int row = (int)(e >> 11), col = (int)(e & 2047);
  if (row >= 3072 && row < 3136) return;  // P2 region, filled by small_p2
  ushort8 o;
  if (row < 3072) {
    const float* src = (row < 2048) ? (W_in + (size_t)row * 2048 + col)
                                    : (Wr1 + (size_t)(row - 2048) * 2048 + col);
    float4 f0 = *(const float4*)(src);
    float4 f1 = *(const float4*)(src + 4);
    o[0] = f2bf(f0.x); o[1] = f2bf(f0.y); o[2] = f2bf(f0.z); o[3] = f2bf(f0.w);
    o[4] = f2bf(f1.x); o[5] = f2bf(f1.y); o[6] = f2bf(f1.z); o[7] = f2bf(f1.w);
  } else {
    o = ushort8{0, 0, 0, 0, 0, 0, 0, 0};
  }
  *(ushort8*)(wbig + (size_t)row * 2048 + col) = o;
}

__global__ __launch_bounds__(256) void conv_ww(const float* __restrict__ W_out,
                                               ushort_t* __restrict__ wwm) {
  size_t e = ((size_t)blockIdx.x * 256 + threadIdx.x) * 8;
  int n = (int)(e >> 11), c = (int)(e & 2047);
  float4 f0 = *(const float4*)(W_out + (size_t)n * 4096 + c);
  float4 f1 = *(const float4*)(W_out + (size_t)n * 4096 + c + 4);
  ushort8 o;
  o[0] = f2bf(f0.x); o[1] = f2bf(f0.y); o[2] = f2bf(f0.z); o[3] = f2bf(f0.w);
  o[4] = f2bf(f1.x); o[5] = f2bf(f1.y); o[6] = f2bf(f1.z); o[7] = f2bf(f1.w);
  *(ushort8*)(wwm + (size_t)n * 2112 + c) = o;
}

// P2[s][k] = sum_j p_norm[s][j] * W_in[j][k]  -> bf16 into wbig rows 3072+s
__global__ __launch_bounds__(256) void small_p2(const float* __restrict__ p_norm,
                                                const float* __restrict__ W_in,
                                                ushort_t* __restrict__ wbig) {
  __shared__ float pn[8][128];
  const int t = threadIdx.x;
  const int k = blockIdx.x * 128 + (t & 127);
  const int sh = t >> 7;  // 0/1
  const int s0 = blockIdx.y * 8;
  float acc[4] = {0.f, 0.f, 0.f, 0.f};
  for (int j0 = 0; j0 < 2048; j0 += 128) {
    __syncthreads();
    {
      int sl = t >> 5;           // 0..7
      int j4 = (t & 31) * 4;     // 0..124
      *(float4*)&pn[sl][j4] = *(const float4*)&p_norm[(size_t)(s0 + sl) * 2048 + j0 + j4];
    }
    __syncthreads();
    #pragma unroll 8
    for (int jj = 0; jj < 128; ++jj) {
      float wv = W_in[(size_t)(j0 + jj) * 2048 + k];
      #pragma unroll
      for (int i = 0; i < 4; ++i) acc[i] += pn[sh * 4 + i][jj] * wv;
    }
  }
  #pragma unroll
  for (int i = 0; i < 4; ++i)
    wbig[(size_t)(3072 + s0 + sh * 4 + i) * 2048 + k] = f2bf(acc[i]);
}

// Rt[n][s] = sum_k protos[s][k] * W_out[n][2048+k] -> bf16 into wwm cols 2048+s
__global__ __launch_bounds__(256) void small_R(const float* __restrict__ protos,
                                               const float* __restrict__ W_out,
                                               ushort_t* __restrict__ wwm) {
  __shared__ float pch[64][68];
  __shared__ float wch[16][68];
  const int t = threadIdx.x;
  const int n_loc = t >> 4;  // 0..15
  const int sb = t & 15;
  const int n0 = blockIdx.x * 16;
  float acc[4] = {0.f, 0.f, 0.f, 0.f};
  for (int k0 = 0; k0 < 2048; k0 += 64) {
    __syncthreads();
    #pragma unroll
    for (int ii = 0; ii < 4; ++ii) {
      int lin4 = t * 4 + ii;      // 0..1023
      int s = lin4 >> 4;          // 0..63
      int k4 = (lin4 & 15) * 4;
      *(float4*)&pch[s][k4] = *(const float4*)&protos[(size_t)s * 2048 + k0 + k4];
    }
    {
      int n_l = t >> 4;
      int k4 = (t & 15) * 4;
      *(float4*)&wch[n_l][k4] = *(const float4*)&W_out[(size_t)(n0 + n_l) * 4096 + 2048 + k0 + k4];
    }
    __syncthreads();
    #pragma unroll 8
    for (int kk = 0; kk < 64; ++kk) {
      float wv = wch[n_loc][kk];
      #pragma unroll
      for (int i = 0; i < 4; ++i) acc[i] += pch[sb + 16 * i][kk] * wv;
    }
  }
  #pragma unroll
  for (int i = 0; i < 4; ++i)
    wwm[(size_t)(n0 + n_loc) * 2112 + 2048 + sb + 16 * i] = f2bf(acc[i]);
}

// ---------------- HEAD GEMM (bf16, m97 structure, BK=32; R12 + occupancy bump) ----------
// __launch_bounds__(256,4): 4 waves/EU target -> total VGPR+AGPR <= 128/wave
// (acc = 64 AGPR; R12's 76 VGPR + 64 AGPR = 140 capped residency at 3 waves/SIMD = the
// measured 31% occupancy). One extra wave/SIMD = +33% TLP to hide the staging stall.
__global__ __launch_bounds__(256, 4) void gemm_head(
    const ushort_t* __restrict__ A, const ushort_t* __restrict__ Bw,
    const float* __restrict__ bias0, const float* __restrict__ bias1,
    float* __restrict__ rn2part, ushort_t* __restrict__ out1, float* __restrict__ out2) {
  __shared__ ushort_t As[128 * 32];
  __shared__ ushort_t Bs[128 * 32];
  const int tid = threadIdx.x;
  const int w = tid >> 6, l = tid & 63;
  const int bm = blockIdx.x * 128;
  const int bn = blockIdx.y * 128;
  const int srow = tid >> 2;
  const int scol = (tid & 3) * 8;
  const int wm = (w >> 1) * 64, wn = (w & 1) * 64;
  const int lr = l & 15, lk = (l >> 4) * 8;

  f32x4 acc[4][4];
  #pragma unroll
  for (int i = 0; i < 4; ++i)
    #pragma unroll
    for (int j = 0; j < 4; ++j) acc[i][j] = f32x4{0.f, 0.f, 0.f, 0.f};

  for (int k0 = 0; k0 < 2048; k0 += 32) {
    __syncthreads();
    #pragma unroll
    for (int r = 0; r < 2; ++r) {
      int row = srow + r * 64;
      gload_lds16(A + (size_t)(bm + row) * 2112 + k0 + scol,
                  (char*)As + (size_t)(r * 256 + tid) * 16);
    }
    #pragma unroll
    for (int r = 0; r < 2; ++r) {
      int row = srow + r * 64;
      gload_lds16(Bw + (size_t)(bn + row) * 2048 + k0 + scol,
                  (char*)Bs + (size_t)(r * 256 + tid) * 16);
    }
    __syncthreads();
    bf16x8 af[4], bf_[4];
    #pragma unroll
    for (int i = 0; i < 4; ++i) af[i] = *(const bf16x8*)&As[(wm + i * 16 + lr) * 32 + lk];
    #pragma unroll
    for (int j = 0; j < 4; ++j) bf_[j] = *(const bf16x8*)&Bs[(wn + j * 16 + lr) * 32 + lk];
    #pragma unroll
    for (int i = 0; i < 4; ++i)
      #pragma unroll
      for (int j = 0; j < 4; ++j)
        acc[i][j] = __builtin_amdgcn_mfma_f32_16x16x32_bf16(af[i], bf_[j], acc[i][j], 0, 0, 0);
  }

  const int lg = l >> 4;
  #pragma unroll
  for (int i = 0; i < 4; ++i) {
    #pragma unroll
    for (int q = 0; q < 4; ++q) {
      const int grow = bm + wm + i * 16 + lg * 4 + q;
      float ss = 0.f;
      #pragma unroll
      for (int j = 0; j < 4; ++j) {
        const int gcol = bn + wn + j * 16 + lr;
        float v = acc[i][j][q];
        if (gcol < 2048) {
          v += bias0[gcol];
          ss += v * v;
        } else if (gcol < 3072) {
          v += bias1[gcol - 2048];
          out1[(size_t)grow * 1024 + (gcol - 2048)] = f2bf(gelu_exact(v));
        } else if (gcol < 3136) {
          out2[(size_t)grow * 64 + (gcol - 3072)] = v;
        }
      }
      if (bn < 2048) {
        ss += __shfl_xor(ss, 1);
        ss += __shfl_xor(ss, 2);
        ss += __shfl_xor(ss, 4);
        ss += __shfl_xor(ss, 8);
        if (lr == 0) rn2part[(size_t)grow * 16 + blockIdx.y] = ss;
      }
    }
  }
}

// ---------------- OUT GEMM (bf16, m97 structure; residual from bf16 xa; occupancy bump) --
__global__ __launch_bounds__(256, 4) void gemm_out(
    const ushort_t* __restrict__ A, const ushort_t* __restrict__ Bw,
    const float* __restrict__ bias0, float* __restrict__ out0) {
  __shared__ ushort_t As[128 * 32];
  __shared__ ushort_t Bs[128 * 32];
  const int tid = threadIdx.x;
  const int w = tid >> 6, l = tid & 63;
  const int bm = blockIdx.x * 128;
  const int bn = blockIdx.y * 128;
  const int srow = tid >> 2;
  const int scol = (tid & 3) * 8;
  const int wm = (w >> 1) * 64, wn = (w & 1) * 64;
  const int lr = l & 15, lk = (l >> 4) * 8;

  f32x4 acc[4][4];
  #pragma unroll
  for (int i = 0; i < 4; ++i)
    #pragma unroll
    for (int j = 0; j < 4; ++j) acc[i][j] = f32x4{0.f, 0.f, 0.f, 0.f};

  for (int k0 = 0; k0 < 2112; k0 += 32) {
    __syncthreads();
    #pragma unroll
    for (int r = 0; r < 2; ++r) {
      int row = srow + r * 64;
      gload_lds16(A + (size_t)(bm + row) * 2112 + k0 + scol,
                  (char*)As + (size_t)(r * 256 + tid) * 16);
    }
    #pragma unroll
    for (int r = 0; r < 2; ++r) {
      int row = srow + r * 64;
      gload_lds16(Bw + (size_t)(bn + row) * 2112 + k0 + scol,
                  (char*)Bs + (size_t)(r * 256 + tid) * 16);
    }
    __syncthreads();
    bf16x8 af[4], bf_[4];
    #pragma unroll
    for (int i = 0; i < 4; ++i) af[i] = *(const bf16x8*)&As[(wm + i * 16 + lr) * 32 + lk];
    #pragma unroll
    for (int j = 0; j < 4; ++j) bf_[j] = *(const bf16x8*)&Bs[(wn + j * 16 + lr) * 32 + lk];
    #pragma unroll
    for (int i = 0; i < 4; ++i)
      #pragma unroll
      for (int j = 0; j < 4; ++j)
        acc[i][j] = __builtin_amdgcn_mfma_f32_16x16x32_bf16(af[i], bf_[j], acc[i][j], 0, 0, 0);
  }

  const int lg = l >> 4;
  #pragma unroll
  for (int i = 0; i < 4; ++i)
    #pragma unroll
    for (int j = 0; j < 4; ++j)
      #pragma unroll
      for (int q = 0; q < 4; ++q) {
        const int grow = bm + wm + i * 16 + lg * 4 + q;
        const int gcol = bn + wn + j * 16 + lr;
        float v = acc[i][j][q] + bias0[gcol];
        float g = gelu_exact(v);
        out0[(size_t)grow * 2048 + gcol] = g + bf2f(A[(size_t)grow * 2112 + gcol]);
      }
}

// ---------------- attention / salience kernel (1 wave per row) ----------------
__global__ __launch_bounds__(256) void attn_k(
    const ushort_t* __restrict__ r_bf, const float* __restrict__ Wr2,
    const float* __restrict__ br2, const float* __restrict__ rn2p,
    const float* __restrict__ rproj, const float* __restrict__ dvec,
    const float* __restrict__ base, const float* __restrict__ cs,
    ushort_t* __restrict__ xa) {
  const int b = blockIdx.x * 4 + (threadIdx.x >> 6);
  const int l = threadIdx.x & 63;
  const ushort_t* rrow = r_bf + (size_t)b * 1024;
  float t0 = 0.f, t1 = 0.f, t2 = 0.f, t3 = 0.f;
  #pragma unroll
  for (int m = 0; m < 16; ++m) {
    int k = l + m * 64;
    float rv = bf2f(rrow[k]);
    t0 += rv * Wr2[k];
    t1 += rv * Wr2[1024 + k];
    t2 += rv * Wr2[2048 + k];
    t3 += rv * Wr2[3072 + k];
  }
  #pragma unroll
  for (int d = 1; d < 64; d <<= 1) {
    t0 += __shfl_xor(t0, d); t1 += __shfl_xor(t1, d);
    t2 += __shfl_xor(t2, d); t3 += __shfl_xor(t3, d);
  }
  t0 += br2[0]; t1 += br2[1]; t2 += br2[2]; t3 += br2[3];
  float mx = fmaxf(fmaxf(t0, t1), fmaxf(t2, t3));
  float e0 = expf(t0 - mx), e1 = expf(t1 - mx), e2 = expf(t2 - mx), e3 = expf(t3 - mx);
  float sinv = 1.f / (e0 + e1 + e2 + e3);
  float tw0 = e0 * sinv, tw1 = e1 * sinv, tw2 = e2 * sinv, tw3 = e3 * sinv;
  const int ty = l >> 4;
  float twv = (ty == 0) ? tw0 : ((ty == 1) ? tw1 : ((ty == 2) ? tw2 : tw3));

  float rsum = 0.f;
  #pragma unroll
  for (int t = 0; t < 16; ++t) rsum += rn2p[(size_t)b * 16 + t];
  float inv = 1.f / fmaxf(sqrtf(rsum), 1e-12f);
  float rp = rproj[(size_t)b * 64 + l] + dvec[l];
  float sal = cs[l] * twv * (rp * inv) + base[l];
  sal = fminf(fmaxf(sal, 0.f), 1.f);
  float logit = sal * (1.f / 0.07f);
  float lm = logit;
  #pragma unroll
  for (int d = 1; d < 64; d <<= 1) lm = fmaxf(lm, __shfl_xor(lm, d));
  float ex = expf(logit - lm);
  float es = ex;
  #pragma unroll
  for (int d = 1; d < 64; d <<= 1) es += __shfl_xor(es, d);
  float attn = ex / es;
  xa[(size_t)b * 2112 + 2048 + l] = f2bf(attn);
}

// ---------------- LayerNorm (in-place on d_out) ----------------
__global__ __launch_bounds__(256) void ln_k(float* __restrict__ y,
                                            const float* __restrict__ lw,
                                            const float* __restrict__ lb) {
  const int b = blockIdx.x, t = threadIdx.x;
  float* row = y + (size_t)b * 2048;
  float4 v0 = *(const float4*)(row + t * 8);
  float4 v1 = *(const float4*)(row + t * 8 + 4);
  float s = v0.x + v0.y + v0.z + v0.w + v1.x + v1.y + v1.z + v1.w;
  float s2 = v0.x * v0.x + v0.y * v0.y + v0.z * v0.z + v0.w * v0.w +
             v1.x * v1.x + v1.y * v1.y + v1.z * v1.z + v1.w * v1.w;
  #pragma unroll
  for (int d = 1; d < 64; d <<= 1) { s += __shfl_xor(s, d); s2 += __shfl_xor(s2, d); }
  __shared__ float red[8];
  if ((t & 63) == 0) { red[t >> 6] = s; red[4 + (t >> 6)] = s2; }
  __syncthreads();
  float ts = red[0] + red[1] + red[2] + red[3];
  float ts2 = red[4] + red[5] + red[6] + red[7];
  const float mu = ts * (1.f / 2048.f);
  const float inv = 1.f / sqrtf(ts2 * (1.f / 2048.f) - mu * mu + 1e-5f);
  float4 w0 = *(const float4*)(lw + t * 8), w1 = *(const float4*)(lw + t * 8 + 4);
  float4 b0 = *(const float4*)(lb + t * 8), b1 = *(const float4*)(lb + t * 8 + 4);
  float4 o0, o1;
  o0.x = (v0.x - mu) * inv * w0.x + b0.x;
  o0.y = (v0.y - mu) * inv * w0.y + b0.y;
  o0.z = (v0.z - mu) * inv * w0.z + b0.z;
  o0.w = (v0.w - mu) * inv * w0.w + b0.w;
  o1.x = (v1.x - mu) * inv * w1.x + b1.x;
  o1.y = (v1.y - mu) * inv * w1.y + b1.y;
  o1.z = (v1.z - mu) * inv * w1.z + b1.z;
  o1.w = (v1.w - mu) * inv * w1.w + b1.w;
  *(float4*)(row + t * 8) = o0;
  *(float4*)(row + t * 8 + 4) = o1;
}

// ---------------- launch ----------------
extern "C" void kernel_launch(void* const* d_in, const int* in_sizes, int n_in,
                              void* d_out, int out_size, void* d_ws, size_t ws_size,
                              hipStream_t stream) {
  const float* x      = (const float*)d_in[0];
  const float* protos = (const float*)d_in[1];
  const float* conf   = (const float*)d_in[2];
  const float* age    = (const float*)d_in[3];
  const float* ev     = (const float*)d_in[4];
  const float* W_in   = (const float*)d_in[5];
  const float* b_in   = (const float*)d_in[6];
  const float* Wr1    = (const float*)d_in[7];
  const float* br1    = (const float*)d_in[8];
  const float* Wr2    = (const float*)d_in[9];
  const float* br2    = (const float*)d_in[10];
  const float* W_out  = (const float*)d_in[11];
  const float* b_out  = (const float*)d_in[12];
  const float* ln_w   = (const float*)d_in[13];
  const float* ln_b   = (const float*)d_in[14];
  float* out = (float*)d_out;

  char* ws = (char*)d_ws;
  size_t off = 0;
  auto take = [&](size_t bytes) {
    char* p = ws + off;
    off = (off + bytes + 255) & ~(size_t)255;
    return p;
  };
  ushort_t* xa     = (ushort_t*)take((size_t)16384 * 2112 * 2);
  ushort_t* wbig   = (ushort_t*)take((size_t)3200 * 2048 * 2);
  ushort_t* wwm    = (ushort_t*)take((size_t)2048 * 2112 * 2);
  ushort_t* rbf    = (ushort_t*)take((size_t)16384 * 1024 * 2);
  float*    rproj  = (float*)take((size_t)16384 * 64 * 4);
  float*    rn2p   = (float*)take((size_t)16384 * 16 * 4);
  float*    pnorm  = (float*)take((size_t)64 * 2048 * 4);
  float*    base   = (float*)take(256);
  float*    cs     = (float*)take(256);
  float*    dvec   = (float*)take(256);
  (void)in_sizes; (void)n_in; (void)out_size; (void)ws_size;

  prep_scal<<<1, 64, 0, stream>>>(conf, age, ev, base, cs);
  prep_pnorm<<<64, 256, 0, stream>>>(protos, b_in, pnorm, dvec);
  conv_x<<<16384, 256, 0, stream>>>(x, xa);
  conv_wbig<<<3200, 256, 0, stream>>>(W_in, Wr1, wbig);
  conv_ww<<<2048, 256, 0, stream>>>(W_out, wwm);
  small_p2<<<dim3(16, 8), 256, 0, stream>>>(pnorm, W_in, wbig);
  small_R<<<128, 256, 0, stream>>>(protos, W_out, wwm);
  // HEAD GEMM: M=16384, N=3200 (rows 3136-3199 zero), K=2048
  gemm_head<<<dim3(128, 25), 256, 0, stream>>>(xa, wbig, b_in, br1, rn2p, rbf, rproj);
  attn_k<<<4096, 256, 0, stream>>>(rbf, Wr2, br2, rn2p, rproj, dvec, base, cs, xa);
  // OUT GEMM: M=16384, N=2048, K=2112
  gemm_out<<<dim3(128, 16), 256, 0, stream>>>(xa, wwm, b_out, out);
  ln_k<<<16384, 256, 0, stream>>>(out, ln_w, ln_b);
}

// Round 15
// 825.584 us; speedup vs baseline: 1.1182x; 1.0046x over previous
//
#include <hip/hip_runtime.h>
#include <hip/hip_bf16.h>
#include <cstdint>

#define DEV __device__ __forceinline__

typedef __bf16 bf16x8 __attribute__((ext_vector_type(8)));
typedef float f32x4 __attribute__((ext_vector_type(4)));
typedef unsigned short ushort_t;
typedef ushort_t ushort8 __attribute__((ext_vector_type(8)));

DEV ushort_t f2bf(float f) {
  union { float f; uint32_t u; } x; x.f = f;
  uint32_t r = (x.u + 0x7fffu + ((x.u >> 16) & 1u)) >> 16;
  return (ushort_t)r;
}
DEV float bf2f(ushort_t b) {
  union { uint32_t u; float f; } x; x.u = ((uint32_t)b) << 16;
  return x.f;
}
DEV float gelu_exact(float v) {
  return 0.5f * v * (1.0f + erff(v * 0.70710678118654752f));
}
DEV void gload_lds16(const void* g, void* l) {
  __builtin_amdgcn_global_load_lds(
      (const __attribute__((address_space(1))) void*)g,
      (__attribute__((address_space(3))) void*)l, 16, 0, 0);
}

// ---------------- prep kernels ----------------

__global__ __launch_bounds__(64) void prep_scal(
    const float* __restrict__ conf, const float* __restrict__ age,
    const float* __restrict__ ev, float* __restrict__ base, float* __restrict__ cs) {
  int l = threadIdx.x;  // 64
  float e = ev[l];
  float m = e;
  #pragma unroll
  for (int d = 1; d < 64; d <<= 1) m = fmaxf(m, __shfl_xor(m, d));
  float freq = logf(e + 1.f) / (logf(m + 2.f) + 1e-8f);
  base[l] = 0.2f * expf(-age[l] * (1.f / 200.f)) + 0.15f * freq + 0.1f * conf[l] + 0.09f;
  cs[l] = 0.45f * conf[l];
}

__global__ __launch_bounds__(256) void prep_pnorm(
    const float* __restrict__ protos, const float* __restrict__ b_in,
    float* __restrict__ p_norm, float* __restrict__ dvec) {
  const int s = blockIdx.x, t = threadIdx.x;
  const float* p = protos + (size_t)s * 2048;
  float vals[8];
  float ss = 0.f, sb = 0.f;
  #pragma unroll
  for (int ii = 0; ii < 2; ++ii) {
    float4 v = *(const float4*)(p + t * 8 + ii * 4);
    float4 bi = *(const float4*)(b_in + t * 8 + ii * 4);
    vals[ii * 4 + 0] = v.x; vals[ii * 4 + 1] = v.y; vals[ii * 4 + 2] = v.z; vals[ii * 4 + 3] = v.w;
    ss += v.x * v.x + v.y * v.y + v.z * v.z + v.w * v.w;
    sb += v.x * bi.x + v.y * bi.y + v.z * bi.z + v.w * bi.w;
  }
  #pragma unroll
  for (int d = 1; d < 64; d <<= 1) { ss += __shfl_xor(ss, d); sb += __shfl_xor(sb, d); }
  __shared__ float red[8];
  if ((t & 63) == 0) { red[t >> 6] = ss; red[4 + (t >> 6)] = sb; }
  __syncthreads();
  ss = red[0] + red[1] + red[2] + red[3];
  sb = red[4] + red[5] + red[6] + red[7];
  float inv = 1.f / fmaxf(sqrtf(ss), 1e-12f);
  #pragma unroll
  for (int k = 0; k < 8; ++k) p_norm[(size_t)s * 2048 + t * 8 + k] = vals[k] * inv;
  if (t == 0) dvec[s] = sb * inv;
}

// ---------------- conversion kernels ----------------

__global__ __launch_bounds__(256) void conv_x(const float* __restrict__ x, ushort_t* __restrict__ xa) {
  size_t e = ((size_t)blockIdx.x * 256 + threadIdx.x) * 8;
  int row = (int)(e >> 11), col = (int)(e & 2047);
  float4 f0 = *(const float4*)(x + e);
  float4 f1 = *(const float4*)(x + e + 4);
  ushort8 o;
  o[0] = f2bf(f0.x); o[1] = f2bf(f0.y); o[2] = f2bf(f0.z); o[3] = f2bf(f0.w);
  o[4] = f2bf(f1.x); o[5] = f2bf(f1.y); o[6] = f2bf(f1.z); o[7] = f2bf(f1.w);
  *(ushort8*)(xa + (size_t)row * 2112 + col) = o;
}

__global__ __launch_bounds__(256) void conv_wbig(const float* __restrict__ W_in,
                                                 const float* __restrict__ Wr1,
                                                 ushort_t* __restrict__ wbig) {
  size_t e = ((size_t)blockIdx.x * 256 + threadIdx.x) * 8;
  int row = (int)(e >> 11), col = (int)(e & 2047);
  if (row >= 3072 && row < 3136) return;  // P2 region, filled by small_p2
  ushort8 o;
  if (row < 3072) {
    const float* src = (row < 2048) ? (W_in + (size_t)row * 2048 + col)
                                    : (Wr1 + (size_t)(row - 2048) * 2048 + col);
    float4 f0 = *(const float4*)(src);
    float4 f1 = *(const float4*)(src + 4);
    o[0] = f2bf(f0.x); o[1] = f2bf(f0.y); o[2] = f2bf(f0.z); o[3] = f2bf(f0.w);
    o[4] = f2bf(f1.x); o[5] = f2bf(f1.y); o[6] = f2bf(f1.z); o[7] = f2bf(f1.w);
  } else {
    o = ushort8{0, 0, 0, 0, 0, 0, 0, 0};
  }
  *(ushort8*)(wbig + (size_t)row * 2048 + col) = o;
}

__global__ __launch_bounds__(256) void conv_ww(const float* __restrict__ W_out,
                                               ushort_t* __restrict__ wwm) {
  size_t e = ((size_t)blockIdx.x * 256 + threadIdx.x) * 8;
  int n = (int)(e >> 11), c = (int)(e & 2047);
  float4 f0 = *(const float4*)(W_out + (size_t)n * 4096 + c);
  float4 f1 = *(const float4*)(W_out + (size_t)n * 4096 + c + 4);
  ushort8 o;
  o[0] = f2bf(f0.x); o[1] = f2bf(f0.y); o[2] = f2bf(f0.z); o[3] = f2bf(f0.w);
  o[4] = f2bf(f1.x); o[5] = f2bf(f1.y); o[6] = f2bf(f1.z); o[7] = f2bf(f1.w);
  *(ushort8*)(wwm + (size_t)n * 2112 + c) = o;
}

// P2[s][k] = sum_j p_norm[s][j] * W_in[j][k]  -> bf16 into wbig rows 3072+s
__global__ __launch_bounds__(256) void small_p2(const float* __restrict__ p_norm,
                                                const float* __restrict__ W_in,
                                                ushort_t* __restrict__ wbig) {
  __shared__ float pn[8][128];
  const int t = threadIdx.x;
  const int k = blockIdx.x * 128 + (t & 127);
  const int sh = t >> 7;  // 0/1
  const int s0 = blockIdx.y * 8;
  float acc[4] = {0.f, 0.f, 0.f, 0.f};
  for (int j0 = 0; j0 < 2048; j0 += 128) {
    __syncthreads();
    {
      int sl = t >> 5;           // 0..7
      int j4 = (t & 31) * 4;     // 0..124
      *(float4*)&pn[sl][j4] = *(const float4*)&p_norm[(size_t)(s0 + sl) * 2048 + j0 + j4];
    }
    __syncthreads();
    #pragma unroll 8
    for (int jj = 0; jj < 128; ++jj) {
      float wv = W_in[(size_t)(j0 + jj) * 2048 + k];
      #pragma unroll
      for (int i = 0; i < 4; ++i) acc[i] += pn[sh * 4 + i][jj] * wv;
    }
  }
  #pragma unroll
  for (int i = 0; i < 4; ++i)
    wbig[(size_t)(3072 + s0 + sh * 4 + i) * 2048 + k] = f2bf(acc[i]);
}

// Rt[n][s] = sum_k protos[s][k] * W_out[n][2048+k] -> bf16 into wwm cols 2048+s
__global__ __launch_bounds__(256) void small_R(const float* __restrict__ protos,
                                               const float* __restrict__ W_out,
                                               ushort_t* __restrict__ wwm) {
  __shared__ float pch[64][68];
  __shared__ float wch[16][68];
  const int t = threadIdx.x;
  const int n_loc = t >> 4;  // 0..15
  const int sb = t & 15;
  const int n0 = blockIdx.x * 16;
  float acc[4] = {0.f, 0.f, 0.f, 0.f};
  for (int k0 = 0; k0 < 2048; k0 += 64) {
    __syncthreads();
    #pragma unroll
    for (int ii = 0; ii < 4; ++ii) {
      int lin4 = t * 4 + ii;      // 0..1023
      int s = lin4 >> 4;          // 0..63
      int k4 = (lin4 & 15) * 4;
      *(float4*)&pch[s][k4] = *(const float4*)&protos[(size_t)s * 2048 + k0 + k4];
    }
    {
      int n_l = t >> 4;
      int k4 = (t & 15) * 4;
      *(float4*)&wch[n_l][k4] = *(const float4*)&W_out[(size_t)(n0 + n_l) * 4096 + 2048 + k0 + k4];
    }
    __syncthreads();
    #pragma unroll 8
    for (int kk = 0; kk < 64; ++kk) {
      float wv = wch[n_loc][kk];
      #pragma unroll
      for (int i = 0; i < 4; ++i) acc[i] += pch[sb + 16 * i][kk] * wv;
    }
  }
  #pragma unroll
  for (int i = 0; i < 4; ++i)
    wwm[(size_t)(n0 + n_loc) * 2112 + 2048 + sb + 16 * i] = f2bf(acc[i]);
}

// ---------------- HEAD GEMM (bf16, 256x128 tile, BK=32, 512 threads / 8 waves) ----------
// R14 structure with doubled BM: arithmetic intensity 64 -> 87 FLOP per staged byte
// (2*256*128*32 FLOP / 24KB), and total staged bytes drop ~27% (B panels re-read half
// as often). Wave grid 4x2: wm=(w>>1)*64, wn=(w&1)*64; per-wave acc[4][4] (64 AGPR)
// unchanged -> launch_bounds(512,4) keeps 4 waves/SIMD.
// Staging: 1024 A-chunks + 512 B-chunks of 16B; thread t stages A chunks t, t+512
// (rows srow, srow+128) and B chunk t (row srow).
__global__ __launch_bounds__(512, 4) void gemm_head(
    const ushort_t* __restrict__ A, const ushort_t* __restrict__ Bw,
    const float* __restrict__ bias0, const float* __restrict__ bias1,
    float* __restrict__ rn2part, ushort_t* __restrict__ out1, float* __restrict__ out2) {
  __shared__ ushort_t As[256 * 32];  // 16 KB
  __shared__ ushort_t Bs[128 * 32];  // 8 KB
  const int tid = threadIdx.x;
  const int w = tid >> 6, l = tid & 63;
  const int bm = blockIdx.x * 256;
  const int bn = blockIdx.y * 128;
  const int srow = tid >> 2;          // 0..127
  const int scol = (tid & 3) * 8;
  const int wm = (w >> 1) * 64, wn = (w & 1) * 64;
  const int lr = l & 15, lk = (l >> 4) * 8;

  f32x4 acc[4][4];
  #pragma unroll
  for (int i = 0; i < 4; ++i)
    #pragma unroll
    for (int j = 0; j < 4; ++j) acc[i][j] = f32x4{0.f, 0.f, 0.f, 0.f};

  for (int k0 = 0; k0 < 2048; k0 += 32) {
    __syncthreads();
    gload_lds16(A + (size_t)(bm + srow) * 2112 + k0 + scol,
                (char*)As + (size_t)tid * 16);
    gload_lds16(A + (size_t)(bm + 128 + srow) * 2112 + k0 + scol,
                (char*)As + (size_t)(512 + tid) * 16);
    gload_lds16(Bw + (size_t)(bn + srow) * 2048 + k0 + scol,
                (char*)Bs + (size_t)tid * 16);
    __syncthreads();
    bf16x8 af[4], bf_[4];
    #pragma unroll
    for (int i = 0; i < 4; ++i) af[i] = *(const bf16x8*)&As[(wm + i * 16 + lr) * 32 + lk];
    #pragma unroll
    for (int j = 0; j < 4; ++j) bf_[j] = *(const bf16x8*)&Bs[(wn + j * 16 + lr) * 32 + lk];
    #pragma unroll
    for (int i = 0; i < 4; ++i)
      #pragma unroll
      for (int j = 0; j < 4; ++j)
        acc[i][j] = __builtin_amdgcn_mfma_f32_16x16x32_bf16(af[i], bf_[j], acc[i][j], 0, 0, 0);
  }

  const int lg = l >> 4;
  #pragma unroll
  for (int i = 0; i < 4; ++i) {
    #pragma unroll
    for (int q = 0; q < 4; ++q) {
      const int grow = bm + wm + i * 16 + lg * 4 + q;
      float ss = 0.f;
      #pragma unroll
      for (int j = 0; j < 4; ++j) {
        const int gcol = bn + wn + j * 16 + lr;
        float v = acc[i][j][q];
        if (gcol < 2048) {
          v += bias0[gcol];
          ss += v * v;
        } else if (gcol < 3072) {
          v += bias1[gcol - 2048];
          out1[(size_t)grow * 1024 + (gcol - 2048)] = f2bf(gelu_exact(v));
        } else if (gcol < 3136) {
          out2[(size_t)grow * 64 + (gcol - 3072)] = v;
        }
      }
      if (bn < 2048) {
        ss += __shfl_xor(ss, 1);
        ss += __shfl_xor(ss, 2);
        ss += __shfl_xor(ss, 4);
        ss += __shfl_xor(ss, 8);
        if (lr == 0) rn2part[(size_t)grow * 16 + blockIdx.y] = ss;
      }
    }
  }
}

// ---------------- OUT GEMM (bf16, 256x128 tile; residual from bf16 xa) ----------------
__global__ __launch_bounds__(512, 4) void gemm_out(
    const ushort_t* __restrict__ A, const ushort_t* __restrict__ Bw,
    const float* __restrict__ bias0, float* __restrict__ out0) {
  __shared__ ushort_t As[256 * 32];
  __shared__ ushort_t Bs[128 * 32];
  const int tid = threadIdx.x;
  const int w = tid >> 6, l = tid & 63;
  const int bm = blockIdx.x * 256;
  const int bn = blockIdx.y * 128;
  const int srow = tid >> 2;
  const int scol = (tid & 3) * 8;
  const int wm = (w >> 1) * 64, wn = (w & 1) * 64;
  const int lr = l & 15, lk = (l >> 4) * 8;

  f32x4 acc[4][4];
  #pragma unroll
  for (int i = 0; i < 4; ++i)
    #pragma unroll
    for (int j = 0; j < 4; ++j) acc[i][j] = f32x4{0.f, 0.f, 0.f, 0.f};

  for (int k0 = 0; k0 < 2112; k0 += 32) {
    __syncthreads();
    gload_lds16(A + (size_t)(bm + srow) * 2112 + k0 + scol,
                (char*)As + (size_t)tid * 16);
    gload_lds16(A + (size_t)(bm + 128 + srow) * 2112 + k0 + scol,
                (char*)As + (size_t)(512 + tid) * 16);
    gload_lds16(Bw + (size_t)(bn + srow) * 2112 + k0 + scol,
                (char*)Bs + (size_t)tid * 16);
    __syncthreads();
    bf16x8 af[4], bf_[4];
    #pragma unroll
    for (int i = 0; i < 4; ++i) af[i] = *(const bf16x8*)&As[(wm + i * 16 + lr) * 32 + lk];
    #pragma unroll
    for (int j = 0; j < 4; ++j) bf_[j] = *(const bf16x8*)&Bs[(wn + j * 16 + lr) * 32 + lk];
    #pragma unroll
    for (int i = 0; i < 4; ++i)
      #pragma unroll
      for (int j = 0; j < 4; ++j)
        acc[i][j] = __builtin_amdgcn_mfma_f32_16x16x32_bf16(af[i], bf_[j], acc[i][j], 0, 0, 0);
  }

  const int lg = l >> 4;
  #pragma unroll
  for (int i = 0; i < 4; ++i)
    #pragma unroll
    for (int j = 0; j < 4; ++j)
      #pragma unroll
      for (int q = 0; q < 4; ++q) {
        const int grow = bm + wm + i * 16 + lg * 4 + q;
        const int gcol = bn + wn + j * 16 + lr;
        float v = acc[i][j][q] + bias0[gcol];
        float g = gelu_exact(v);
        out0[(size_t)grow * 2048 + gcol] = g + bf2f(A[(size_t)grow * 2112 + gcol]);
      }
}

// ---------------- attention / salience kernel (1 wave per row) ----------------
__global__ __launch_bounds__(256) void attn_k(
    const ushort_t* __restrict__ r_bf, const float* __restrict__ Wr2,
    const float* __restrict__ br2, const float* __restrict__ rn2p,
    const float* __restrict__ rproj, const float* __restrict__ dvec,
    const float* __restrict__ base, const float* __restrict__ cs,
    ushort_t* __restrict__ xa) {
  const int b = blockIdx.x * 4 + (threadIdx.x >> 6);
  const int l = threadIdx.x & 63;
  const ushort_t* rrow = r_bf + (size_t)b * 1024;
  float t0 = 0.f, t1 = 0.f, t2 = 0.f, t3 = 0.f;
  #pragma unroll
  for (int m = 0; m < 16; ++m) {
    int k = l + m * 64;
    float rv = bf2f(rrow[k]);
    t0 += rv * Wr2[k];
    t1 += rv * Wr2[1024 + k];
    t2 += rv * Wr2[2048 + k];
    t3 += rv * Wr2[3072 + k];
  }
  #pragma unroll
  for (int d = 1; d < 64; d <<= 1) {
    t0 += __shfl_xor(t0, d); t1 += __shfl_xor(t1, d);
    t2 += __shfl_xor(t2, d); t3 += __shfl_xor(t3, d);
  }
  t0 += br2[0]; t1 += br2[1]; t2 += br2[2]; t3 += br2[3];
  float mx = fmaxf(fmaxf(t0, t1), fmaxf(t2, t3));
  float e0 = expf(t0 - mx), e1 = expf(t1 - mx), e2 = expf(t2 - mx), e3 = expf(t3 - mx);
  float sinv = 1.f / (e0 + e1 + e2 + e3);
  float tw0 = e0 * sinv, tw1 = e1 * sinv, tw2 = e2 * sinv, tw3 = e3 * sinv;
  const int ty = l >> 4;
  float twv = (ty == 0) ? tw0 : ((ty == 1) ? tw1 : ((ty == 2) ? tw2 : tw3));

  float rsum = 0.f;
  #pragma unroll
  for (int t = 0; t < 16; ++t) rsum += rn2p[(size_t)b * 16 + t];
  float inv = 1.f / fmaxf(sqrtf(rsum), 1e-12f);
  float rp = rproj[(size_t)b * 64 + l] + dvec[l];
  float sal = cs[l] * twv * (rp * inv) + base[l];
  sal = fminf(fmaxf(sal, 0.f), 1.f);
  float logit = sal * (1.f / 0.07f);
  float lm = logit;
  #pragma unroll
  for (int d = 1; d < 64; d <<= 1) lm = fmaxf(lm, __shfl_xor(lm, d));
  float ex = expf(logit - lm);
  float es = ex;
  #pragma unroll
  for (int d = 1; d < 64; d <<= 1) es += __shfl_xor(es, d);
  float attn = ex / es;
  xa[(size_t)b * 2112 + 2048 + l] = f2bf(attn);
}

// ---------------- LayerNorm (in-place on d_out) ----------------
__global__ __launch_bounds__(256) void ln_k(float* __restrict__ y,
                                            const float* __restrict__ lw,
                                            const float* __restrict__ lb) {
  const int b = blockIdx.x, t = threadIdx.x;
  float* row = y + (size_t)b * 2048;
  float4 v0 = *(const float4*)(row + t * 8);
  float4 v1 = *(const float4*)(row + t * 8 + 4);
  float s = v0.x + v0.y + v0.z + v0.w + v1.x + v1.y + v1.z + v1.w;
  float s2 = v0.x * v0.x + v0.y * v0.y + v0.z * v0.z + v0.w * v0.w +
             v1.x * v1.x + v1.y * v1.y + v1.z * v1.z + v1.w * v1.w;
  #pragma unroll
  for (int d = 1; d < 64; d <<= 1) { s += __shfl_xor(s, d); s2 += __shfl_xor(s2, d); }
  __shared__ float red[8];
  if ((t & 63) == 0) { red[t >> 6] = s; red[4 + (t >> 6)] = s2; }
  __syncthreads();
  float ts = red[0] + red[1] + red[2] + red[3];
  float ts2 = red[4] + red[5] + red[6] + red[7];
  const float mu = ts * (1.f / 2048.f);
  const float inv = 1.f / sqrtf(ts2 * (1.f / 2048.f) - mu * mu + 1e-5f);
  float4 w0 = *(const float4*)(lw + t * 8), w1 = *(const float4*)(lw + t * 8 + 4);
  float4 b0 = *(const float4*)(lb + t * 8), b1 = *(const float4*)(lb + t * 8 + 4);
  float4 o0, o1;
  o0.x = (v0.x - mu) * inv * w0.x + b0.x;
  o0.y = (v0.y - mu) * inv * w0.y + b0.y;
  o0.z = (v0.z - mu) * inv * w0.z + b0.z;
  o0.w = (v0.w - mu) * inv * w0.w + b0.w;
  o1.x = (v1.x - mu) * inv * w1.x + b1.x;
  o1.y = (v1.y - mu) * inv * w1.y + b1.y;
  o1.z = (v1.z - mu) * inv * w1.z + b1.z;
  o1.w = (v1.w - mu) * inv * w1.w + b1.w;
  *(float4*)(row + t * 8) = o0;
  *(float4*)(row + t * 8 + 4) = o1;
}

// ---------------- launch ----------------
extern "C" void kernel_launch(void* const* d_in, const int* in_sizes, int n_in,
                              void* d_out, int out_size, void* d_ws, size_t ws_size,
                              hipStream_t stream) {
  const float* x      = (const float*)d_in[0];
  const float* protos = (const float*)d_in[1];
  const float* conf   = (const float*)d_in[2];
  const float* age    = (const float*)d_in[3];
  const float* ev     = (const float*)d_in[4];
  const float* W_in   = (const float*)d_in[5];
  const float* b_in   = (const float*)d_in[6];
  const float* Wr1    = (const float*)d_in[7];
  const float* br1    = (const float*)d_in[8];
  const float* Wr2    = (const float*)d_in[9];
  const float* br2    = (const float*)d_in[10];
  const float* W_out  = (const float*)d_in[11];
  const float* b_out  = (const float*)d_in[12];
  const float* ln_w   = (const float*)d_in[13];
  const float* ln_b   = (const float*)d_in[14];
  float* out = (float*)d_out;

  char* ws = (char*)d_ws;
  size_t off = 0;
  auto take = [&](size_t bytes) {
    char* p = ws + off;
    off = (off + bytes + 255) & ~(size_t)255;
    return p;
  };
  ushort_t* xa     = (ushort_t*)take((size_t)16384 * 2112 * 2);
  ushort_t* wbig   = (ushort_t*)take((size_t)3200 * 2048 * 2);
  ushort_t* wwm    = (ushort_t*)take((size_t)2048 * 2112 * 2);
  ushort_t* rbf    = (ushort_t*)take((size_t)16384 * 1024 * 2);
  float*    rproj  = (float*)take((size_t)16384 * 64 * 4);
  float*    rn2p   = (float*)take((size_t)16384 * 16 * 4);
  float*    pnorm  = (float*)take((size_t)64 * 2048 * 4);
  float*    base   = (float*)take(256);
  float*    cs     = (float*)take(256);
  float*    dvec   = (float*)take(256);
  (void)in_sizes; (void)n_in; (void)out_size; (void)ws_size;

  prep_scal<<<1, 64, 0, stream>>>(conf, age, ev, base, cs);
  prep_pnorm<<<64, 256, 0, stream>>>(protos, b_in, pnorm, dvec);
  conv_x<<<16384, 256, 0, stream>>>(x, xa);
  conv_wbig<<<3200, 256, 0, stream>>>(W_in, Wr1, wbig);
  conv_ww<<<2048, 256, 0, stream>>>(W_out, wwm);
  small_p2<<<dim3(16, 8), 256, 0, stream>>>(pnorm, W_in, wbig);
  small_R<<<128, 256, 0, stream>>>(protos, W_out, wwm);
  // HEAD GEMM: M=16384 (64 x 256-row tiles), N=3200 (25 x 128-col tiles), K=2048
  gemm_head<<<dim3(64, 25), 512, 0, stream>>>(xa, wbig, b_in, br1, rn2p, rbf, rproj);
  attn_k<<<4096, 256, 0, stream>>>(rbf, Wr2, br2, rn2p, rproj, dvec, base, cs, xa);
  // OUT GEMM: M=16384, N=2048 (16 tiles), K=2112
  gemm_out<<<dim3(64, 16), 512, 0, stream>>>(xa, wwm, b_out, out);
  ln_k<<<16384, 256, 0, stream>>>(out, ln_w, ln_b);
}

// Round 16
// 819.875 us; speedup vs baseline: 1.1260x; 1.0070x over previous
//
#include <hip/hip_runtime.h>
#include <hip/hip_bf16.h>
#include <cstdint>

#define DEV __device__ __forceinline__

typedef __bf16 bf16x8 __attribute__((ext_vector_type(8)));
typedef float f32x4 __attribute__((ext_vector_type(4)));
typedef unsigned short ushort_t;
typedef ushort_t ushort8 __attribute__((ext_vector_type(8)));

DEV ushort_t f2bf(float f) {
  union { float f; uint32_t u; } x; x.f = f;
  uint32_t r = (x.u + 0x7fffu + ((x.u >> 16) & 1u)) >> 16;
  return (ushort_t)r;
}
DEV float bf2f(ushort_t b) {
  union { uint32_t u; float f; } x; x.u = ((uint32_t)b) << 16;
  return x.f;
}
DEV float gelu_exact(float v) {
  return 0.5f * v * (1.0f + erff(v * 0.70710678118654752f));
}
DEV void gload_lds16(const void* g, void* l) {
  __builtin_amdgcn_global_load_lds(
      (const __attribute__((address_space(1))) void*)g,
      (__attribute__((address_space(3))) void*)l, 16, 0, 0);
}

// ---------------- prep kernels ----------------

__global__ __launch_bounds__(64) void prep_scal(
    const float* __restrict__ conf, const float* __restrict__ age,
    const float* __restrict__ ev, float* __restrict__ base, float* __restrict__ cs) {
  int l = threadIdx.x;  // 64
  float e = ev[l];
  float m = e;
  #pragma unroll
  for (int d = 1; d < 64; d <<= 1) m = fmaxf(m, __shfl_xor(m, d));
  float freq = logf(e + 1.f) / (logf(m + 2.f) + 1e-8f);
  base[l] = 0.2f * expf(-age[l] * (1.f / 200.f)) + 0.15f * freq + 0.1f * conf[l] + 0.09f;
  cs[l] = 0.45f * conf[l];
}

__global__ __launch_bounds__(256) void prep_pnorm(
    const float* __restrict__ protos, const float* __restrict__ b_in,
    float* __restrict__ p_norm, float* __restrict__ dvec) {
  const int s = blockIdx.x, t = threadIdx.x;
  const float* p = protos + (size_t)s * 2048;
  float vals[8];
  float ss = 0.f, sb = 0.f;
  #pragma unroll
  for (int ii = 0; ii < 2; ++ii) {
    float4 v = *(const float4*)(p + t * 8 + ii * 4);
    float4 bi = *(const float4*)(b_in + t * 8 + ii * 4);
    vals[ii * 4 + 0] = v.x; vals[ii * 4 + 1] = v.y; vals[ii * 4 + 2] = v.z; vals[ii * 4 + 3] = v.w;
    ss += v.x * v.x + v.y * v.y + v.z * v.z + v.w * v.w;
    sb += v.x * bi.x + v.y * bi.y + v.z * bi.z + v.w * bi.w;
  }
  #pragma unroll
  for (int d = 1; d < 64; d <<= 1) { ss += __shfl_xor(ss, d); sb += __shfl_xor(sb, d); }
  __shared__ float red[8];
  if ((t & 63) == 0) { red[t >> 6] = ss; red[4 + (t >> 6)] = sb; }
  __syncthreads();
  ss = red[0] + red[1] + red[2] + red[3];
  sb = red[4] + red[5] + red[6] + red[7];
  float inv = 1.f / fmaxf(sqrtf(ss), 1e-12f);
  #pragma unroll
  for (int k = 0; k < 8; ++k) p_norm[(size_t)s * 2048 + t * 8 + k] = vals[k] * inv;
  if (t == 0) dvec[s] = sb * inv;
}

// ---------------- conversion kernels ----------------

__global__ __launch_bounds__(256) void conv_x(const float* __restrict__ x, ushort_t* __restrict__ xa) {
  size_t e = ((size_t)blockIdx.x * 256 + threadIdx.x) * 8;
  int row = (int)(e >> 11), col = (int)(e & 2047);
  float4 f0 = *(const float4*)(x + e);
  float4 f1 = *(const float4*)(x + e + 4);
  ushort8 o;
  o[0] = f2bf(f0.x); o[1] = f2bf(f0.y); o[2] = f2bf(f0.z); o[3] = f2bf(f0.w);
  o[4] = f2bf(f1.x); o[5] = f2bf(f1.y); o[6] = f2bf(f1.z); o[7] = f2bf(f1.w);
  *(ushort8*)(xa + (size_t)row * 2112 + col) = o;
}

__global__ __launch_bounds__(256) void conv_wbig(const float* __restrict__ W_in,
                                                 const float* __restrict__ Wr1,
                                                 ushort_t* __restrict__ wbig) {
  size_t e = ((size_t)blockIdx.x * 256 + threadIdx.x) * 8;
  int row = (int)(e >> 11), col = (int)(e & 2047);
  if (row >= 3072 && row < 3136) return;  // P2 region, filled by small_p2
  ushort8 o;
  if (row < 3072) {
    const float* src = (row < 2048) ? (W_in + (size_t)row * 2048 + col)
                                    : (Wr1 + (size_t)(row - 2048) * 2048 + col);
    float4 f0 = *(const float4*)(src);
    float4 f1 = *(const float4*)(src + 4);
    o[0] = f2bf(f0.x); o[1] = f2bf(f0.y); o[2] = f2bf(f0.z); o[3] = f2bf(f0.w);
    o[4] = f2bf(f1.x); o[5] = f2bf(f1.y); o[6] = f2bf(f1.z); o[7] = f2bf(f1.w);
  } else {
    o = ushort8{0, 0, 0, 0, 0, 0, 0, 0};
  }
  *(ushort8*)(wbig + (size_t)row * 2048 + col) = o;
}

__global__ __launch_bounds__(256) void conv_ww(const float* __restrict__ W_out,
                                               ushort_t* __restrict__ wwm) {
  size_t e = ((size_t)blockIdx.x * 256 + threadIdx.x) * 8;
  int n = (int)(e >> 11), c = (int)(e & 2047);
  float4 f0 = *(const float4*)(W_out + (size_t)n * 4096 + c);
  float4 f1 = *(const float4*)(W_out + (size_t)n * 4096 + c + 4);
  ushort8 o;
  o[0] = f2bf(f0.x); o[1] = f2bf(f0.y); o[2] = f2bf(f0.z); o[3] = f2bf(f0.w);
  o[4] = f2bf(f1.x); o[5] = f2bf(f1.y); o[6] = f2bf(f1.z); o[7] = f2bf(f1.w);
  *(ushort8*)(wwm + (size_t)n * 2112 + c) = o;
}

// P2[s][k] = sum_j p_norm[s][j] * W_in[j][k]  -> bf16 into wbig rows 3072+s
__global__ __launch_bounds__(256) void small_p2(const float* __restrict__ p_norm,
                                                const float* __restrict__ W_in,
                                                ushort_t* __restrict__ wbig) {
  __shared__ float pn[8][128];
  const int t = threadIdx.x;
  const int k = blockIdx.x * 128 + (t & 127);
  const int sh = t >> 7;  // 0/1
  const int s0 = blockIdx.y * 8;
  float acc[4] = {0.f, 0.f, 0.f, 0.f};
  for (int j0 = 0; j0 < 2048; j0 += 128) {
    __syncthreads();
    {
      int sl = t >> 5;           // 0..7
      int j4 = (t & 31) * 4;     // 0..124
      *(float4*)&pn[sl][j4] = *(const float4*)&p_norm[(size_t)(s0 + sl) * 2048 + j0 + j4];
    }
    __syncthreads();
    #pragma unroll 8
    for (int jj = 0; jj < 128; ++jj) {
      float wv = W_in[(size_t)(j0 + jj) * 2048 + k];
      #pragma unroll
      for (int i = 0; i < 4; ++i) acc[i] += pn[sh * 4 + i][jj] * wv;
    }
  }
  #pragma unroll
  for (int i = 0; i < 4; ++i)
    wbig[(size_t)(3072 + s0 + sh * 4 + i) * 2048 + k] = f2bf(acc[i]);
}

// Rt[n][s] = sum_k protos[s][k] * W_out[n][2048+k] -> bf16 into wwm cols 2048+s
__global__ __launch_bounds__(256) void small_R(const float* __restrict__ protos,
                                               const float* __restrict__ W_out,
                                               ushort_t* __restrict__ wwm) {
  __shared__ float pch[64][68];
  __shared__ float wch[16][68];
  const int t = threadIdx.x;
  const int n_loc = t >> 4;  // 0..15
  const int sb = t & 15;
  const int n0 = blockIdx.x * 16;
  float acc[4] = {0.f, 0.f, 0.f, 0.f};
  for (int k0 = 0; k0 < 2048; k0 += 64) {
    __syncthreads();
    #pragma unroll
    for (int ii = 0; ii < 4; ++ii) {
      int lin4 = t * 4 + ii;      // 0..1023
      int s = lin4 >> 4;          // 0..63
      int k4 = (lin4 & 15) * 4;
      *(float4*)&pch[s][k4] = *(const float4*)&protos[(size_t)s * 2048 + k0 + k4];
    }
    {
      int n_l = t >> 4;
      int k4 = (t & 15) * 4;
      *(float4*)&wch[n_l][k4] = *(const float4*)&W_out[(size_t)(n0 + n_l) * 4096 + 2048 + k0 + k4];
    }
    __syncthreads();
    #pragma unroll 8
    for (int kk = 0; kk < 64; ++kk) {
      float wv = wch[n_loc][kk];
      #pragma unroll
      for (int i = 0; i < 4; ++i) acc[i] += pch[sb + 16 * i][kk] * wv;
    }
  }
  #pragma unroll
  for (int i = 0; i < 4; ++i)
    wwm[(size_t)(n0 + n_loc) * 2112 + 2048 + sb + 16 * i] = f2bf(acc[i]);
}

// ---------------- HEAD GEMM (bf16, 256x128, BK=32, BANK-SWIZZLED LDS reads) ----------
// R15 + 2-bit XOR chunk swizzle. Diagnosis: rows are 64B (16 banks), so the fragment
// read bank = (lr&1)*16 + lg*4 -- 8 lanes per 4-bank slot = 8-way conflict on every
// ds_read_b128 (2.6e7 conflict counter, MfmaUtil pinned ~25%). Fix (rule #21,
// both-sides-or-neither): stage with inverse-swizzled GLOBAL source
// (chunk ^= (row>>1)&3 at 16B granularity, LDS dest linear), read logical chunk lg at
// stored position lg ^ ((lr>>1)&3). Banks become 8 slots x 2-way; 2-way is free (m136).
// ((row>>1)&3 == (lr>>1)&3 since wm, i*16 are multiples of 16.)
__global__ __launch_bounds__(512, 4) void gemm_head(
    const ushort_t* __restrict__ A, const ushort_t* __restrict__ Bw,
    const float* __restrict__ bias0, const float* __restrict__ bias1,
    float* __restrict__ rn2part, ushort_t* __restrict__ out1, float* __restrict__ out2) {
  __shared__ ushort_t As[256 * 32];  // 16 KB
  __shared__ ushort_t Bs[128 * 32];  // 8 KB
  const int tid = threadIdx.x;
  const int w = tid >> 6, l = tid & 63;
  const int bm = blockIdx.x * 256;
  const int bn = blockIdx.y * 128;
  const int srow = tid >> 2;                                   // 0..127
  const int scol = ((tid & 3) ^ ((srow >> 1) & 3)) * 8;        // inverse-swizzled source
  const int wm = (w >> 1) * 64, wn = (w & 1) * 64;
  const int lr = l & 15;
  const int lk = ((l >> 4) ^ ((lr >> 1) & 3)) * 8;             // swizzled read position

  f32x4 acc[4][4];
  #pragma unroll
  for (int i = 0; i < 4; ++i)
    #pragma unroll
    for (int j = 0; j < 4; ++j) acc[i][j] = f32x4{0.f, 0.f, 0.f, 0.f};

  for (int k0 = 0; k0 < 2048; k0 += 32) {
    __syncthreads();
    gload_lds16(A + (size_t)(bm + srow) * 2112 + k0 + scol,
                (char*)As + (size_t)tid * 16);
    gload_lds16(A + (size_t)(bm + 128 + srow) * 2112 + k0 + scol,
                (char*)As + (size_t)(512 + tid) * 16);
    gload_lds16(Bw + (size_t)(bn + srow) * 2048 + k0 + scol,
                (char*)Bs + (size_t)tid * 16);
    __syncthreads();
    bf16x8 af[4], bf_[4];
    #pragma unroll
    for (int i = 0; i < 4; ++i) af[i] = *(const bf16x8*)&As[(wm + i * 16 + lr) * 32 + lk];
    #pragma unroll
    for (int j = 0; j < 4; ++j) bf_[j] = *(const bf16x8*)&Bs[(wn + j * 16 + lr) * 32 + lk];
    #pragma unroll
    for (int i = 0; i < 4; ++i)
      #pragma unroll
      for (int j = 0; j < 4; ++j)
        acc[i][j] = __builtin_amdgcn_mfma_f32_16x16x32_bf16(af[i], bf_[j], acc[i][j], 0, 0, 0);
  }

  const int lg = l >> 4;
  #pragma unroll
  for (int i = 0; i < 4; ++i) {
    #pragma unroll
    for (int q = 0; q < 4; ++q) {
      const int grow = bm + wm + i * 16 + lg * 4 + q;
      float ss = 0.f;
      #pragma unroll
      for (int j = 0; j < 4; ++j) {
        const int gcol = bn + wn + j * 16 + lr;
        float v = acc[i][j][q];
        if (gcol < 2048) {
          v += bias0[gcol];
          ss += v * v;
        } else if (gcol < 3072) {
          v += bias1[gcol - 2048];
          out1[(size_t)grow * 1024 + (gcol - 2048)] = f2bf(gelu_exact(v));
        } else if (gcol < 3136) {
          out2[(size_t)grow * 64 + (gcol - 3072)] = v;
        }
      }
      if (bn < 2048) {
        ss += __shfl_xor(ss, 1);
        ss += __shfl_xor(ss, 2);
        ss += __shfl_xor(ss, 4);
        ss += __shfl_xor(ss, 8);
        if (lr == 0) rn2part[(size_t)grow * 16 + blockIdx.y] = ss;
      }
    }
  }
}

// ---------------- OUT GEMM (bf16, 256x128, bank-swizzled; residual from bf16 xa) --------
__global__ __launch_bounds__(512, 4) void gemm_out(
    const ushort_t* __restrict__ A, const ushort_t* __restrict__ Bw,
    const float* __restrict__ bias0, float* __restrict__ out0) {
  __shared__ ushort_t As[256 * 32];
  __shared__ ushort_t Bs[128 * 32];
  const int tid = threadIdx.x;
  const int w = tid >> 6, l = tid & 63;
  const int bm = blockIdx.x * 256;
  const int bn = blockIdx.y * 128;
  const int srow = tid >> 2;
  const int scol = ((tid & 3) ^ ((srow >> 1) & 3)) * 8;
  const int wm = (w >> 1) * 64, wn = (w & 1) * 64;
  const int lr = l & 15;
  const int lk = ((l >> 4) ^ ((lr >> 1) & 3)) * 8;

  f32x4 acc[4][4];
  #pragma unroll
  for (int i = 0; i < 4; ++i)
    #pragma unroll
    for (int j = 0; j < 4; ++j) acc[i][j] = f32x4{0.f, 0.f, 0.f, 0.f};

  for (int k0 = 0; k0 < 2112; k0 += 32) {
    __syncthreads();
    gload_lds16(A + (size_t)(bm + srow) * 2112 + k0 + scol,
                (char*)As + (size_t)tid * 16);
    gload_lds16(A + (size_t)(bm + 128 + srow) * 2112 + k0 + scol,
                (char*)As + (size_t)(512 + tid) * 16);
    gload_lds16(Bw + (size_t)(bn + srow) * 2112 + k0 + scol,
                (char*)Bs + (size_t)tid * 16);
    __syncthreads();
    bf16x8 af[4], bf_[4];
    #pragma unroll
    for (int i = 0; i < 4; ++i) af[i] = *(const bf16x8*)&As[(wm + i * 16 + lr) * 32 + lk];
    #pragma unroll
    for (int j = 0; j < 4; ++j) bf_[j] = *(const bf16x8*)&Bs[(wn + j * 16 + lr) * 32 + lk];
    #pragma unroll
    for (int i = 0; i < 4; ++i)
      #pragma unroll
      for (int j = 0; j < 4; ++j)
        acc[i][j] = __builtin_amdgcn_mfma_f32_16x16x32_bf16(af[i], bf_[j], acc[i][j], 0, 0, 0);
  }

  const int lg = l >> 4;
  #pragma unroll
  for (int i = 0; i < 4; ++i)
    #pragma unroll
    for (int j = 0; j < 4; ++j)
      #pragma unroll
      for (int q = 0; q < 4; ++q) {
        const int grow = bm + wm + i * 16 + lg * 4 + q;
        const int gcol = bn + wn + j * 16 + lr;
        float v = acc[i][j][q] + bias0[gcol];
        float g = gelu_exact(v);
        out0[(size_t)grow * 2048 + gcol] = g + bf2f(A[(size_t)grow * 2112 + gcol]);
      }
}

// ---------------- attention / salience kernel (1 wave per row) ----------------
__global__ __launch_bounds__(256) void attn_k(
    const ushort_t* __restrict__ r_bf, const float* __restrict__ Wr2,
    const float* __restrict__ br2, const float* __restrict__ rn2p,
    const float* __restrict__ rproj, const float* __restrict__ dvec,
    const float* __restrict__ base, const float* __restrict__ cs,
    ushort_t* __restrict__ xa) {
  const int b = blockIdx.x * 4 + (threadIdx.x >> 6);
  const int l = threadIdx.x & 63;
  const ushort_t* rrow = r_bf + (size_t)b * 1024;
  float t0 = 0.f, t1 = 0.f, t2 = 0.f, t3 = 0.f;
  #pragma unroll
  for (int m = 0; m < 16; ++m) {
    int k = l + m * 64;
    float rv = bf2f(rrow[k]);
    t0 += rv * Wr2[k];
    t1 += rv * Wr2[1024 + k];
    t2 += rv * Wr2[2048 + k];
    t3 += rv * Wr2[3072 + k];
  }
  #pragma unroll
  for (int d = 1; d < 64; d <<= 1) {
    t0 += __shfl_xor(t0, d); t1 += __shfl_xor(t1, d);
    t2 += __shfl_xor(t2, d); t3 += __shfl_xor(t3, d);
  }
  t0 += br2[0]; t1 += br2[1]; t2 += br2[2]; t3 += br2[3];
  float mx = fmaxf(fmaxf(t0, t1), fmaxf(t2, t3));
  float e0 = expf(t0 - mx), e1 = expf(t1 - mx), e2 = expf(t2 - mx), e3 = expf(t3 - mx);
  float sinv = 1.f / (e0 + e1 + e2 + e3);
  float tw0 = e0 * sinv, tw1 = e1 * sinv, tw2 = e2 * sinv, tw3 = e3 * sinv;
  const int ty = l >> 4;
  float twv = (ty == 0) ? tw0 : ((ty == 1) ? tw1 : ((ty == 2) ? tw2 : tw3));

  float rsum = 0.f;
  #pragma unroll
  for (int t = 0; t < 16; ++t) rsum += rn2p[(size_t)b * 16 + t];
  float inv = 1.f / fmaxf(sqrtf(rsum), 1e-12f);
  float rp = rproj[(size_t)b * 64 + l] + dvec[l];
  float sal = cs[l] * twv * (rp * inv) + base[l];
  sal = fminf(fmaxf(sal, 0.f), 1.f);
  float logit = sal * (1.f / 0.07f);
  float lm = logit;
  #pragma unroll
  for (int d = 1; d < 64; d <<= 1) lm = fmaxf(lm, __shfl_xor(lm, d));
  float ex = expf(logit - lm);
  float es = ex;
  #pragma unroll
  for (int d = 1; d < 64; d <<= 1) es += __shfl_xor(es, d);
  float attn = ex / es;
  xa[(size_t)b * 2112 + 2048 + l] = f2bf(attn);
}

// ---------------- LayerNorm (in-place on d_out) ----------------
__global__ __launch_bounds__(256) void ln_k(float* __restrict__ y,
                                            const float* __restrict__ lw,
                                            const float* __restrict__ lb) {
  const int b = blockIdx.x, t = threadIdx.x;
  float* row = y + (size_t)b * 2048;
  float4 v0 = *(const float4*)(row + t * 8);
  float4 v1 = *(const float4*)(row + t * 8 + 4);
  float s = v0.x + v0.y + v0.z + v0.w + v1.x + v1.y + v1.z + v1.w;
  float s2 = v0.x * v0.x + v0.y * v0.y + v0.z * v0.z + v0.w * v0.w +
             v1.x * v1.x + v1.y * v1.y + v1.z * v1.z + v1.w * v1.w;
  #pragma unroll
  for (int d = 1; d < 64; d <<= 1) { s += __shfl_xor(s, d); s2 += __shfl_xor(s2, d); }
  __shared__ float red[8];
  if ((t & 63) == 0) { red[t >> 6] = s; red[4 + (t >> 6)] = s2; }
  __syncthreads();
  float ts = red[0] + red[1] + red[2] + red[3];
  float ts2 = red[4] + red[5] + red[6] + red[7];
  const float mu = ts * (1.f / 2048.f);
  const float inv = 1.f / sqrtf(ts2 * (1.f / 2048.f) - mu * mu + 1e-5f);
  float4 w0 = *(const float4*)(lw + t * 8), w1 = *(const float4*)(lw + t * 8 + 4);
  float4 b0 = *(const float4*)(lb + t * 8), b1 = *(const float4*)(lb + t * 8 + 4);
  float4 o0, o1;
  o0.x = (v0.x - mu) * inv * w0.x + b0.x;
  o0.y = (v0.y - mu) * inv * w0.y + b0.y;
  o0.z = (v0.z - mu) * inv * w0.z + b0.z;
  o0.w = (v0.w - mu) * inv * w0.w + b0.w;
  o1.x = (v1.x - mu) * inv * w1.x + b1.x;
  o1.y = (v1.y - mu) * inv * w1.y + b1.y;
  o1.z = (v1.z - mu) * inv * w1.z + b1.z;
  o1.w = (v1.w - mu) * inv * w1.w + b1.w;
  *(float4*)(row + t * 8) = o0;
  *(float4*)(row + t * 8 + 4) = o1;
}

// ---------------- launch ----------------
extern "C" void kernel_launch(void* const* d_in, const int* in_sizes, int n_in,
                              void* d_out, int out_size, void* d_ws, size_t ws_size,
                              hipStream_t stream) {
  const float* x      = (const float*)d_in[0];
  const float* protos = (const float*)d_in[1];
  const float* conf   = (const float*)d_in[2];
  const float* age    = (const float*)d_in[3];
  const float* ev     = (const float*)d_in[4];
  const float* W_in   = (const float*)d_in[5];
  const float* b_in   = (const float*)d_in[6];
  const float* Wr1    = (const float*)d_in[7];
  const float* br1    = (const float*)d_in[8];
  const float* Wr2    = (const float*)d_in[9];
  const float* br2    = (const float*)d_in[10];
  const float* W_out  = (const float*)d_in[11];
  const float* b_out  = (const float*)d_in[12];
  const float* ln_w   = (const float*)d_in[13];
  const float* ln_b   = (const float*)d_in[14];
  float* out = (float*)d_out;

  char* ws = (char*)d_ws;
  size_t off = 0;
  auto take = [&](size_t bytes) {
    char* p = ws + off;
    off = (off + bytes + 255) & ~(size_t)255;
    return p;
  };
  ushort_t* xa     = (ushort_t*)take((size_t)16384 * 2112 * 2);
  ushort_t* wbig   = (ushort_t*)take((size_t)3200 * 2048 * 2);
  ushort_t* wwm    = (ushort_t*)take((size_t)2048 * 2112 * 2);
  ushort_t* rbf    = (ushort_t*)take((size_t)16384 * 1024 * 2);
  float*    rproj  = (float*)take((size_t)16384 * 64 * 4);
  float*    rn2p   = (float*)take((size_t)16384 * 16 * 4);
  float*    pnorm  = (float*)take((size_t)64 * 2048 * 4);
  float*    base   = (float*)take(256);
  float*    cs     = (float*)take(256);
  float*    dvec   = (float*)take(256);
  (void)in_sizes; (void)n_in; (void)out_size; (void)ws_size;

  prep_scal<<<1, 64, 0, stream>>>(conf, age, ev, base, cs);
  prep_pnorm<<<64, 256, 0, stream>>>(protos, b_in, pnorm, dvec);
  conv_x<<<16384, 256, 0, stream>>>(x, xa);
  conv_wbig<<<3200, 256, 0, stream>>>(W_in, Wr1, wbig);
  conv_ww<<<2048, 256, 0, stream>>>(W_out, wwm);
  small_p2<<<dim3(16, 8), 256, 0, stream>>>(pnorm, W_in, wbig);
  small_R<<<128, 256, 0, stream>>>(protos, W_out, wwm);
  // HEAD GEMM: M=16384 (64 x 256-row tiles), N=3200 (25 x 128-col tiles), K=2048
  gemm_head<<<dim3(64, 25), 512, 0, stream>>>(xa, wbig, b_in, br1, rn2p, rbf, rproj);
  attn_k<<<4096, 256, 0, stream>>>(rbf, Wr2, br2, rn2p, rproj, dvec, base, cs, xa);
  // OUT GEMM: M=16384, N=2048 (16 tiles), K=2112
  gemm_out<<<dim3(64, 16), 512, 0, stream>>>(xa, wwm, b_out, out);
  ln_k<<<16384, 256, 0, stream>>>(out, ln_w, ln_b);
}